// Round 1
// 518.014 us; speedup vs baseline: 1.0083x; 1.0083x over previous
//
#include <hip/hip_runtime.h>

// Problem constants (from reference)
#define N_NODES 20000
#define F_IN    512
#define D_H     256
#define E_EDGES 200000
#define L_LAYERS 3
#define T_ETYPES 2

typedef __attribute__((ext_vector_type(8))) short bf16x8;
typedef __attribute__((ext_vector_type(4))) float f32x4;

__device__ __forceinline__ unsigned short f2b(float f) {
    unsigned int u = __float_as_uint(f);
    u = (u + 0x7FFFu + ((u >> 16) & 1u)) >> 16;   // round-nearest-even
    return (unsigned short)u;
}
__device__ __forceinline__ unsigned int pack2(float a, float b) {
    return (unsigned int)f2b(a) | ((unsigned int)f2b(b) << 16);
}

// ---------------- weight pre-shuffle: fp32 row-major -> bf16 fragment-slab order ----
// For W[NO,K]: slab (n>>7, k>>5) of 128 rows x 32 k is a contiguous 4096-elem block;
// inside, elem (n_local,kk) at ((n_local>>4)&7)<<9 | ((kk>>3)&3)<<7 | (n_local&15)<<3 | (kk&7).
// A wave's 16x32 B-tile t at step s is then the 1KB run: slab + (t&7)*512 + lane*8.
__device__ __forceinline__ void shuf_one(const float* s, unsigned short* d,
                                         int NO, int K, int i)
{
    const int matsz = NO * K;
    const int mat = i / matsz;
    const int rem = i - mat * matsz;
    const int n = rem / K;
    const int k = rem - n * K;
    const int dst = mat * matsz + ((n >> 7) * (K >> 5) + (k >> 5)) * 4096
                  + (((n >> 4) & 7) << 9) + (((k >> 3) & 3) << 7)
                  + ((n & 15) << 3) + (k & 7);
    d[dst] = f2b(s[i]);
}

__global__ __launch_bounds__(256) void shufw_kernel(
    const float* __restrict__ s0, unsigned short* __restrict__ d0, int NO0, int K0, int n0,
    const float* __restrict__ s1, unsigned short* __restrict__ d1, int NO1, int K1, int n1,
    const float* __restrict__ s2, unsigned short* __restrict__ d2, int NO2, int K2, int n2,
    const float* __restrict__ s3, unsigned short* __restrict__ d3, int NO3, int K3, int n3)
{
    int i = blockIdx.x * 256 + threadIdx.x;
    if (i < n0) { shuf_one(s0, d0, NO0, K0, i); return; }
    if ((i -= n0) < n1) { shuf_one(s1, d1, NO1, K1, i); return; }
    if ((i -= n1) < n2) { shuf_one(s2, d2, NO2, K2, i); return; }
    if ((i -= n2) < n3) { shuf_one(s3, d3, NO3, K3, i); return; }
}

// ---------------- barrier-free GEMM, fragment-slab weights, 2-deep SW pipeline ------
// C[M, bn:bn+128] = act(A @ W^T + bias). Block 64x128, 4 waves 2x2, wave 32x64.
// NO LDS, NO barriers: A and B fragments stream global->VGPR with loads issued
// 2 K-steps ahead (triple-buffered registers; all indices compile-time).
template <int A_FP32, int NSTEPS>
__global__ __launch_bounds__(256) void gemm_frag(
    const void* __restrict__ Ap, const unsigned short* __restrict__ Wf,
    const float* __restrict__ bias, unsigned short* __restrict__ Cout,
    int M, int ldc, int relu)
{
    const int K = NSTEPS * 32;
    const int tid  = threadIdx.x;
    const int lane = tid & 63;
    const int w    = tid >> 6;
    const int wm   = w >> 1, wn = w & 1;
    const int bm   = blockIdx.y * 64;
    const int bn   = blockIdx.x * 128;
    // per-wave/lane B base: col-slab + wn*2048 + lane*8
    const unsigned short* slabw = Wf + (size_t)blockIdx.x * NSTEPS * 4096 + (wn << 11) + lane * 8;

    const int r0 = min(bm + wm * 32 + (lane & 15), M - 1);
    const int r1 = min(bm + wm * 32 + 16 + (lane & 15), M - 1);
    const int ko = (lane >> 4) << 3;

    f32x4 acc[2][4] = {};
    bf16x8 Ab[3][2];   // bf16-A path buffers
    float4 Fb[3][4];   // fp32-A path buffers (raw; packed at use time)
    bf16x8 Bb[3][4];

#define GF_LOADB(S, BUF) do { \
    const unsigned short* bp_ = slabw + (size_t)(S) * 4096; \
    Bb[BUF][0] = *(const bf16x8*)(bp_); \
    Bb[BUF][1] = *(const bf16x8*)(bp_ + 512); \
    Bb[BUF][2] = *(const bf16x8*)(bp_ + 1024); \
    Bb[BUF][3] = *(const bf16x8*)(bp_ + 1536); \
} while (0)

#define GF_LOADA(S, BUF) do { \
    if (A_FP32) { \
        const float* p0_ = (const float*)Ap + (size_t)r0 * K + (S) * 32 + ko; \
        const float* p1_ = (const float*)Ap + (size_t)r1 * K + (S) * 32 + ko; \
        Fb[BUF][0] = *(const float4*)p0_; Fb[BUF][1] = *(const float4*)(p0_ + 4); \
        Fb[BUF][2] = *(const float4*)p1_; Fb[BUF][3] = *(const float4*)(p1_ + 4); \
    } else { \
        Ab[BUF][0] = *(const bf16x8*)((const unsigned short*)Ap + (size_t)r0 * K + (S) * 32 + ko); \
        Ab[BUF][1] = *(const bf16x8*)((const unsigned short*)Ap + (size_t)r1 * K + (S) * 32 + ko); \
    } \
} while (0)

#define GF_STEP(BUF) do { \
    bf16x8 af0_, af1_; \
    if (A_FP32) { \
        uint4 u0_, u1_; \
        u0_.x = pack2(Fb[BUF][0].x, Fb[BUF][0].y); u0_.y = pack2(Fb[BUF][0].z, Fb[BUF][0].w); \
        u0_.z = pack2(Fb[BUF][1].x, Fb[BUF][1].y); u0_.w = pack2(Fb[BUF][1].z, Fb[BUF][1].w); \
        u1_.x = pack2(Fb[BUF][2].x, Fb[BUF][2].y); u1_.y = pack2(Fb[BUF][2].z, Fb[BUF][2].w); \
        u1_.z = pack2(Fb[BUF][3].x, Fb[BUF][3].y); u1_.w = pack2(Fb[BUF][3].z, Fb[BUF][3].w); \
        af0_ = *(bf16x8*)&u0_; af1_ = *(bf16x8*)&u1_; \
    } else { af0_ = Ab[BUF][0]; af1_ = Ab[BUF][1]; } \
    _Pragma("unroll") \
    for (int j_ = 0; j_ < 4; ++j_) { \
        acc[0][j_] = __builtin_amdgcn_mfma_f32_16x16x32_bf16(af0_, Bb[BUF][j_], acc[0][j_], 0, 0, 0); \
        acc[1][j_] = __builtin_amdgcn_mfma_f32_16x16x32_bf16(af1_, Bb[BUF][j_], acc[1][j_], 0, 0, 0); \
    } \
} while (0)

    GF_LOADA(0, 0); GF_LOADB(0, 0);
    GF_LOADA(1, 1); GF_LOADB(1, 1);
#pragma unroll
    for (int s = 0; s < NSTEPS; ++s) {
        if (s + 2 < NSTEPS) { GF_LOADA(s + 2, (s + 2) % 3); GF_LOADB(s + 2, (s + 2) % 3); }
        GF_STEP(s % 3);
    }
#undef GF_LOADB
#undef GF_LOADA
#undef GF_STEP

    // C/D layout: col = lane&15, row = (lane>>4)*4 + reg
    const int cbase = bn + wn * 64 + (lane & 15);
    const int rbase = bm + wm * 32 + ((lane >> 4) << 2);
#pragma unroll
    for (int j = 0; j < 4; ++j) {
        const int col = cbase + j * 16;
        const float bj = bias[col];
#pragma unroll
        for (int i = 0; i < 2; ++i)
#pragma unroll
            for (int r = 0; r < 4; ++r) {
                const int row = rbase + i * 16 + r;
                if (row < M) {
                    float v = acc[i][j][r] + bj;
                    if (relu) v = fmaxf(v, 0.f);
                    Cout[(size_t)row * ldc + col] = f2b(v);
                }
            }
    }
}

// ---------------- fused layer tail, BOTH etypes: 4 GEMMs + ReLU + 2x LN + sum -------
// Block 32 rows x 256 cols, 4 waves (wave 32x64), grid 625 exact.
// Uniform 32-step pipelined stream (2-deep prefetch, triple-buffered regs):
//   steps  0..7 : A=h,          B=Wself[t0] -> acc[0]
//   steps  8..15: A=neigh[:,0:],B=Wneigh[t0]-> acc[0]
//   steps 16..23: A=h (L1-hot), B=Wself[t1] -> acc[1]
//   steps 24..31: A=neigh[:,256:],B=Wneigh[t1]-> acc[1]
// Epilogue: per-etype LN, summed; no fp32 partial round-trip.
template <int LAST>
__global__ __launch_bounds__(256) void sage_tail2(
    const unsigned short* __restrict__ h,       // [N,256] bf16
    const unsigned short* __restrict__ neigh,   // [N,512] bf16 (both etypes)
    const unsigned short* __restrict__ Wfs,     // layer base: 2 mats x (2 slabs x 8 steps x 4096)
    const unsigned short* __restrict__ Wfn,
    const float* __restrict__ bias,             // [2*256] at layer offset
    const float* __restrict__ gamma,
    const float* __restrict__ beta,
    void* __restrict__ outp)
{
    __shared__ float sS[2][4][32], sQ[2][4][32];
    const int tid  = threadIdx.x;
    const int lane = tid & 63;
    const int wn   = tid >> 6;
    const int bm   = blockIdx.x * 32;
    const int r0   = bm + (lane & 15);
    const int r1   = r0 + 16;
    const int ko   = (lane >> 4) << 3;
    // tiles tt = wn*4+j (0..15): slab = wn>>1 (stride 8*4096), intile = (wn&1)*4+j
    const int wboff = ((wn >> 1) << 15) + ((wn & 1) << 11) + lane * 8;

    f32x4 acc[2][2][4] = {};   // [etype][rowhalf][j]
    bf16x8 Ab[3][2];
    bf16x8 Bb[3][4];

#define TL_LOAD(S, BUF) do { \
    const int seg_ = (S) >> 3, ss_ = (S) & 7; \
    const unsigned short* Ap_; int lda_; \
    if (seg_ == 0 || seg_ == 2) { Ap_ = h; lda_ = 256; } \
    else if (seg_ == 1)         { Ap_ = neigh; lda_ = 512; } \
    else                        { Ap_ = neigh + 256; lda_ = 512; } \
    Ab[BUF][0] = *(const bf16x8*)(Ap_ + (size_t)r0 * lda_ + ss_ * 32 + ko); \
    Ab[BUF][1] = *(const bf16x8*)(Ap_ + (size_t)r1 * lda_ + ss_ * 32 + ko); \
    const unsigned short* Wb_ = ((seg_ & 1) ? Wfn : Wfs) + ((seg_ >> 1) << 16) + wboff + ss_ * 4096; \
    Bb[BUF][0] = *(const bf16x8*)(Wb_); \
    Bb[BUF][1] = *(const bf16x8*)(Wb_ + 512); \
    Bb[BUF][2] = *(const bf16x8*)(Wb_ + 1024); \
    Bb[BUF][3] = *(const bf16x8*)(Wb_ + 1536); \
} while (0)

#define TL_STEP(S, BUF) do { \
    const int e_ = (S) >> 4; \
    _Pragma("unroll") \
    for (int j_ = 0; j_ < 4; ++j_) { \
        acc[e_][0][j_] = __builtin_amdgcn_mfma_f32_16x16x32_bf16(Ab[BUF][0], Bb[BUF][j_], acc[e_][0][j_], 0, 0, 0); \
        acc[e_][1][j_] = __builtin_amdgcn_mfma_f32_16x16x32_bf16(Ab[BUF][1], Bb[BUF][j_], acc[e_][1][j_], 0, 0, 0); \
    } \
} while (0)

    TL_LOAD(0, 0);
    TL_LOAD(1, 1);
#pragma unroll
    for (int s = 0; s < 32; ++s) {
        if (s + 2 < 32) TL_LOAD(s + 2, (s + 2) % 3);
        TL_STEP(s, s % 3);
    }
#undef TL_LOAD
#undef TL_STEP

    // Epilogue: per-row LN over 256 cols for each etype (wave partial -> LDS combine).
    const int colb = wn * 64 + (lane & 15);
    const int rq   = (lane >> 4) << 2;
    float bia[2][4], gam[2][4], bet[2][4];
#pragma unroll
    for (int e = 0; e < 2; ++e)
#pragma unroll
        for (int j = 0; j < 4; ++j) {
            const int col = e * 256 + colb + j * 16;
            bia[e][j] = bias[col]; gam[e][j] = gamma[col]; bet[e][j] = beta[col];
        }
#pragma unroll
    for (int e = 0; e < 2; ++e)
#pragma unroll
        for (int i = 0; i < 2; ++i)
#pragma unroll
            for (int r = 0; r < 4; ++r) {
                float s = 0.f, q = 0.f;
#pragma unroll
                for (int j = 0; j < 4; ++j) {
                    float v = acc[e][i][j][r] + bia[e][j];
                    if (!LAST) v = fmaxf(v, 0.f);
                    s += v; q += v * v;
                }
#pragma unroll
                for (int o = 1; o < 16; o <<= 1) {
                    s += __shfl_xor(s, o);
                    q += __shfl_xor(q, o);
                }
                if ((lane & 15) == 0) {
                    sS[e][wn][i * 16 + rq + r] = s;
                    sQ[e][wn][i * 16 + rq + r] = q;
                }
            }
    __syncthreads();
#pragma unroll
    for (int i = 0; i < 2; ++i)
#pragma unroll
        for (int r = 0; r < 4; ++r) {
            const int rl = i * 16 + rq + r;
            const int row = bm + rl;
            float mean[2], inv[2];
#pragma unroll
            for (int e = 0; e < 2; ++e) {
                const float st = sS[e][0][rl] + sS[e][1][rl] + sS[e][2][rl] + sS[e][3][rl];
                const float qt = sQ[e][0][rl] + sQ[e][1][rl] + sQ[e][2][rl] + sQ[e][3][rl];
                mean[e] = st * (1.f / 256.f);
                const float var = qt * (1.f / 256.f) - mean[e] * mean[e];
                inv[e] = rsqrtf(var + 1e-5f);
            }
#pragma unroll
            for (int j = 0; j < 4; ++j) {
                const int col = colb + j * 16;
                float o = 0.f;
#pragma unroll
                for (int e = 0; e < 2; ++e) {
                    float v = acc[e][i][j][r] + bia[e][j];
                    if (!LAST) v = fmaxf(v, 0.f);
                    o += (v - mean[e]) * inv[e] * gam[e][j] + bet[e][j];
                }
                if (LAST) ((float*)outp)[(size_t)row * D_H + col] = o;
                else      ((unsigned short*)outp)[(size_t)row * D_H + col] = f2b(o);
            }
        }
}

// ---------------- CSR build (both etypes batched; once per launch) ----------------
__global__ __launch_bounds__(256) void zero_int_kernel(int* p, int n)
{
    int i = blockIdx.x * 256 + threadIdx.x;
    if (i < n) p[i] = 0;
}

__global__ __launch_bounds__(256) void count_deg_kernel(
    const int* __restrict__ dst, int* __restrict__ cnt, int E2)
{
    int e = blockIdx.x * 256 + threadIdx.x;
    if (e < E2) {
        const int base = (e >= E_EDGES) ? N_NODES : 0;
        atomicAdd(&cnt[base + dst[e]], 1);
    }
}

__global__ __launch_bounds__(256) void scanA_kernel(
    const int* __restrict__ cnt, int* __restrict__ incl, int* __restrict__ bsum, int n)
{
    __shared__ int tmp[256];
    const int tid = threadIdx.x;
    const int i = blockIdx.x * 256 + tid;
    const int v = (i < n) ? cnt[i] : 0;
    tmp[tid] = v;
    __syncthreads();
#pragma unroll
    for (int o = 1; o < 256; o <<= 1) {
        const int t = (tid >= o) ? tmp[tid - o] : 0;
        __syncthreads();
        tmp[tid] += t;
        __syncthreads();
    }
    if (i < n) incl[i] = tmp[tid];
    if (tid == 255) bsum[blockIdx.x] = tmp[255];
}

__global__ __launch_bounds__(256) void scanB_kernel(int* __restrict__ bsum, int nb)
{
    __shared__ int tmp[256];
    const int tid = threadIdx.x;
    const int v = (tid < nb) ? bsum[tid] : 0;
    tmp[tid] = v;
    __syncthreads();
#pragma unroll
    for (int o = 1; o < 256; o <<= 1) {
        const int t = (tid >= o) ? tmp[tid - o] : 0;
        __syncthreads();
        tmp[tid] += t;
        __syncthreads();
    }
    if (tid < nb) bsum[tid] = tmp[tid] - v;  // exclusive
}

__global__ __launch_bounds__(256) void scanC_kernel(
    const int* __restrict__ cnt, const int* __restrict__ incl,
    const int* __restrict__ bsum, int* __restrict__ off, int* __restrict__ cursor, int n)
{
    const int i = blockIdx.x * 256 + threadIdx.x;
    if (i < n) {
        const int e = incl[i] + bsum[blockIdx.x];
        off[i + 1] = e;
        cursor[i] = e - cnt[i];
    }
    if (i == 0) off[0] = 0;
}

__global__ __launch_bounds__(256) void fill_csr_kernel(
    const int* __restrict__ src, const int* __restrict__ dst,
    int* __restrict__ cursor, int* __restrict__ esrc, int E2)
{
    int e = blockIdx.x * 256 + threadIdx.x;
    if (e < E2) {
        const int base = (e >= E_EDGES) ? N_NODES : 0;
        const int pos = atomicAdd(&cursor[base + dst[e]], 1);
        esrc[pos] = src[e];
    }
}

// ---------------- segment max (bf16, both etypes): one wave per (node,t) ----------------
__device__ __forceinline__ ushort4 umax4(ushort4 a, ushort4 b)
{
    a.x = a.x > b.x ? a.x : b.x;
    a.y = a.y > b.y ? a.y : b.y;
    a.z = a.z > b.z ? a.z : b.z;
    a.w = a.w > b.w ? a.w : b.w;
    return a;
}

__global__ __launch_bounds__(256) void seg_max_kernel(
    const unsigned short* __restrict__ hp, const int* __restrict__ off,
    const int* __restrict__ esrc, unsigned short* __restrict__ neigh)
{
    const int g = blockIdx.x * 4 + (threadIdx.x >> 6);
    if (g >= 2 * N_NODES) return;
    const int t = (g >= N_NODES) ? 1 : 0;
    const int node = g - t * N_NODES;
    const int lane = threadIdx.x & 63;
    const int co = t * D_H + lane * 4;
    const int e0 = off[g], e1 = off[g + 1];
    ushort4 acc = make_ushort4(0, 0, 0, 0);
    int e = e0;
    for (; e + 4 <= e1; e += 4) {
        const int s0 = esrc[e + 0], s1 = esrc[e + 1];
        const int s2 = esrc[e + 2], s3 = esrc[e + 3];
        const ushort4 v0 = *(const ushort4*)(hp + (size_t)s0 * 512 + co);
        const ushort4 v1 = *(const ushort4*)(hp + (size_t)s1 * 512 + co);
        const ushort4 v2 = *(const ushort4*)(hp + (size_t)s2 * 512 + co);
        const ushort4 v3 = *(const ushort4*)(hp + (size_t)s3 * 512 + co);
        acc = umax4(umax4(umax4(acc, v0), umax4(v1, v2)), v3);
    }
    for (; e < e1; ++e)
        acc = umax4(acc, *(const ushort4*)(hp + (size_t)esrc[e] * 512 + co));
    *(ushort4*)(neigh + (size_t)node * 512 + co) = acc;
}

extern "C" void kernel_launch(void* const* d_in, const int* in_sizes, int n_in,
                              void* d_out, int out_size, void* d_ws, size_t ws_size,
                              hipStream_t stream)
{
    const float* x      = (const float*)d_in[0];
    const int*   src    = (const int*)d_in[1];
    const int*   dst    = (const int*)d_in[2];
    const float* Wlin   = (const float*)d_in[3];
    const float* blin   = (const float*)d_in[4];
    const float* Wpool  = (const float*)d_in[5];
    const float* bpool  = (const float*)d_in[6];
    const float* Wself  = (const float*)d_in[7];
    const float* Wneigh = (const float*)d_in[8];
    const float* bconv  = (const float*)d_in[9];
    const float* gamma  = (const float*)d_in[10];
    const float* beta   = (const float*)d_in[11];

    const size_t NB = (size_t)N_NODES * D_H;  // 5.12M
    char* p = (char*)d_ws;
    unsigned short* hp_b    = (unsigned short*)p; p += NB * 2 * T_ETYPES;  // [N,512]
    unsigned short* neigh_b = (unsigned short*)p; p += NB * 2 * T_ETYPES;  // [N,512]
    unsigned short* h_a     = (unsigned short*)p; p += NB * 2;
    unsigned short* h_b     = (unsigned short*)p; p += NB * 2;
    float*          partial = (float*)p;          p += NB * 4;             // (unused; kept for layout)
    unsigned short* wlin_f  = (unsigned short*)p; p += (size_t)D_H * F_IN * 2;
    const size_t WSZ = (size_t)L_LAYERS * T_ETYPES * D_H * D_H;  // 393216
    unsigned short* wpool_f = (unsigned short*)p; p += WSZ * 2;
    unsigned short* wself_f = (unsigned short*)p; p += WSZ * 2;
    unsigned short* wneigh_f= (unsigned short*)p; p += WSZ * 2;
    int* ip = (int*)p;
    const int NT = T_ETYPES * N_NODES;  // 40000
    int* cnt    = ip; ip += NT;
    int* incl   = ip; ip += NT;
    int* off    = ip; ip += NT + 1;
    int* cursor = ip; ip += NT;
    int* esrc   = ip; ip += T_ETYPES * E_EDGES;
    int* bsum   = ip; ip += 256;
    (void)partial;

    const dim3 blk(256);
    const int E2 = T_ETYPES * E_EDGES;
    const dim3 e2grid((E2 + 255) / 256);
    const dim3 ntgrid((NT + 255) / 256);
    const int nScanBlk = (NT + 255) / 256;  // 157

    // ---- weights -> bf16 fragment-slab order (one dispatch) ----
    {
        const int nlin = D_H * F_IN;          // 131072, NO=256 K=512
        const int nw   = (int)WSZ;            // 393216
        const int tot  = nlin + 3 * nw;
        shufw_kernel<<<dim3((tot + 255) / 256), blk, 0, stream>>>(
            Wlin, wlin_f, D_H, F_IN, nlin,
            Wpool, wpool_f, T_ETYPES * D_H, D_H, nw,   // per layer: [512,256]
            Wself, wself_f, D_H, D_H, nw,              // per (l,t): [256,256]
            Wneigh, wneigh_f, D_H, D_H, nw);
    }

    // ---- CSR build, both etypes batched ----
    zero_int_kernel<<<ntgrid, blk, 0, stream>>>(cnt, NT);
    count_deg_kernel<<<e2grid, blk, 0, stream>>>(dst, cnt, E2);
    scanA_kernel<<<dim3(nScanBlk), blk, 0, stream>>>(cnt, incl, bsum, NT);
    scanB_kernel<<<dim3(1), blk, 0, stream>>>(bsum, nScanBlk);
    scanC_kernel<<<dim3(nScanBlk), blk, 0, stream>>>(cnt, incl, bsum, off, cursor, NT);
    fill_csr_kernel<<<e2grid, blk, 0, stream>>>(src, dst, cursor, esrc, E2);

    // ---- h0 = bf16(x @ Wlin^T + blin) : fp32 A fused-convert, K=512 ----
    gemm_frag<1, 16><<<dim3(2, (N_NODES + 63) / 64), blk, 0, stream>>>(
        x, wlin_f, blin, h_a, N_NODES, D_H, 0);

    unsigned short* h = h_a;
    unsigned short* hn = h_b;
    const dim3 pgrid(4, (N_NODES + 63) / 64);   // pool: 512 cols batched over etypes
    const dim3 sgrid((2 * N_NODES + 3) / 4);
    const dim3 fgrid(N_NODES / 32);             // 625, exact
    for (int l = 0; l < L_LAYERS; ++l) {
        // hp[:, t*256:] = bf16(relu(h @ Wpool[l,t]^T + bpool[l,t])), both t in one dispatch
        gemm_frag<0, 8><<<pgrid, blk, 0, stream>>>(
            h, wpool_f + (size_t)l * T_ETYPES * D_H * D_H, bpool + (size_t)l * T_ETYPES * D_H,
            hp_b, N_NODES, T_ETYPES * D_H, 1);
        // neigh = segment_max per (node, t)
        seg_max_kernel<<<sgrid, blk, 0, stream>>>(hp_b, off, esrc, neigh_b);
        // fused tail, BOTH etypes in one dispatch (no fp32 partial round-trip)
        const size_t wlo = (size_t)l * T_ETYPES * D_H * D_H;
        const size_t blo = (size_t)l * T_ETYPES * D_H;
        if (l < L_LAYERS - 1) {
            sage_tail2<0><<<fgrid, blk, 0, stream>>>(
                h, neigh_b, wself_f + wlo, wneigh_f + wlo,
                bconv + blo, gamma + blo, beta + blo, hn);
        } else {
            sage_tail2<1><<<fgrid, blk, 0, stream>>>(
                h, neigh_b, wself_f + wlo, wneigh_f + wlo,
                bconv + blo, gamma + blo, beta + blo, d_out);
        }
        unsigned short* tmp = h; h = hn; hn = tmp;
    }
}

// Round 2
// 477.916 us; speedup vs baseline: 1.0929x; 1.0839x over previous
//
#include <hip/hip_runtime.h>

// Problem constants (from reference)
#define N_NODES 20000
#define F_IN    512
#define D_H     256
#define E_EDGES 200000
#define L_LAYERS 3
#define T_ETYPES 2

typedef __attribute__((ext_vector_type(8))) short bf16x8;
typedef __attribute__((ext_vector_type(4))) float f32x4;

__device__ __forceinline__ unsigned short f2b(float f) {
    unsigned int u = __float_as_uint(f);
    u = (u + 0x7FFFu + ((u >> 16) & 1u)) >> 16;   // round-nearest-even
    return (unsigned short)u;
}
__device__ __forceinline__ unsigned int pack2(float a, float b) {
    return (unsigned int)f2b(a) | ((unsigned int)f2b(b) << 16);
}

// async global->LDS, 16B per lane; LDS dest = wave-uniform base + lane*16,
// global source is per-lane (this is how we deposit fragment-slab order).
__device__ __forceinline__ void gload16(const unsigned short* g, unsigned short* l)
{
    __builtin_amdgcn_global_load_lds(
        (const __attribute__((address_space(1))) void*)g,
        (__attribute__((address_space(3))) void*)l, 16, 0, 0);
}

// ---------------- weight pre-shuffle: fp32 row-major -> bf16 fragment-slab order ----
// For W[NO,K]: slab (n>>7, k>>5) of 128 rows x 32 k is a contiguous 4096-elem (8KB) block;
// inside, elem (n_local,kk) at ((n_local>>4)&7)<<9 | ((kk>>3)&3)<<7 | (n_local&15)<<3 | (kk&7)
// i.e. 8 subtiles of 16 rows x 32 k, each a 1KB lane-major MFMA fragment run.
__device__ __forceinline__ void shuf_one(const float* s, unsigned short* d,
                                         int NO, int K, int i)
{
    const int matsz = NO * K;
    const int mat = i / matsz;
    const int rem = i - mat * matsz;
    const int n = rem / K;
    const int k = rem - n * K;
    const int dst = mat * matsz + ((n >> 7) * (K >> 5) + (k >> 5)) * 4096
                  + (((n >> 4) & 7) << 9) + (((k >> 3) & 3) << 7)
                  + ((n & 15) << 3) + (k & 7);
    d[dst] = f2b(s[i]);
}

__global__ __launch_bounds__(256) void shufw_kernel(
    const float* __restrict__ s0, unsigned short* __restrict__ d0, int NO0, int K0, int n0,
    const float* __restrict__ s1, unsigned short* __restrict__ d1, int NO1, int K1, int n1,
    const float* __restrict__ s2, unsigned short* __restrict__ d2, int NO2, int K2, int n2,
    const float* __restrict__ s3, unsigned short* __restrict__ d3, int NO3, int K3, int n3)
{
    int i = blockIdx.x * 256 + threadIdx.x;
    if (i < n0) { shuf_one(s0, d0, NO0, K0, i); return; }
    if ((i -= n0) < n1) { shuf_one(s1, d1, NO1, K1, i); return; }
    if ((i -= n1) < n2) { shuf_one(s2, d2, NO2, K2, i); return; }
    if ((i -= n2) < n3) { shuf_one(s3, d3, NO3, K3, i); return; }
}

// ---------------- x fp32 -> bf16 (once) ----------------
__global__ __launch_bounds__(256) void cvt_bf16_kernel(
    const float* __restrict__ in, unsigned short* __restrict__ out, int n8)
{
    const int i = blockIdx.x * 256 + threadIdx.x;
    if (i < n8) {
        const float4 a = ((const float4*)in)[i * 2];
        const float4 b = ((const float4*)in)[i * 2 + 1];
        uint4 u;
        u.x = pack2(a.x, a.y); u.y = pack2(a.z, a.w);
        u.z = pack2(b.x, b.y); u.w = pack2(b.z, b.w);
        ((uint4*)out)[i] = u;
    }
}

// ---------------- m97-style GEMM: LDS double-buffer + global_load_lds ----------------
// C[M, bn:bn+128] = act(A @ W^T + bias). Block 128x128, 4 waves 2x2, wave 64x64.
// A-tile staged into fragment-slab order (8 subtiles x 1KB) via per-lane source addrs;
// B-tile is a verbatim copy of the pre-shuffled weight slab. All ds_reads are
// lane-contiguous 1KB ds_read_b128 runs: conflict-free by construction.
template <int NSTEPS>
__global__ __launch_bounds__(256) void gemm_lds(
    const unsigned short* __restrict__ A,   // [M, K] bf16, K = NSTEPS*32
    const unsigned short* __restrict__ Wf,  // fragment-slab weights, col-slab = blockIdx.x
    const float* __restrict__ bias, unsigned short* __restrict__ Cout,
    int M, int ldc, int relu)
{
    __shared__ __align__(16) unsigned short As[2][4096];  // 8KB per buf
    __shared__ __align__(16) unsigned short Bs[2][4096];
    const int K = NSTEPS * 32;
    const int tid = threadIdx.x, lane = tid & 63, w = tid >> 6;
    const int wm = w >> 1, wn = w & 1;
    const int bm = blockIdx.y * 128, bn = blockIdx.x * 128;
    const unsigned short* slab0 = Wf + (((size_t)blockIdx.x * NSTEPS) << 12);

    // A staging source precompute: chunk c = q*256+tid carries subtile mi=c>>6,
    // row r=(c&63)&15, k-quarter kq=(c&63)>>4 -> per-lane global offset (shorts).
    size_t aoff[2];
#pragma unroll
    for (int q = 0; q < 2; ++q) {
        const int c = q * 256 + tid;
        const int mi = c >> 6, ww = c & 63, r = ww & 15, kq = ww >> 4;
        const int rg = min(bm + mi * 16 + r, M - 1);
        aoff[q] = (size_t)rg * K + kq * 8;
    }

    f32x4 acc[4][4] = {};

#define GL_STAGE(S, BUF) do { \
    _Pragma("unroll") \
    for (int q_ = 0; q_ < 2; ++q_) { \
        gload16(A + aoff[q_] + (S) * 32, &As[BUF][(q_ * 256 + w * 64) * 8]); \
        gload16(slab0 + (((size_t)(S)) << 12) + (size_t)(q_ * 256 + tid) * 8, \
                &Bs[BUF][(q_ * 256 + w * 64) * 8]); \
    } \
} while (0)

    GL_STAGE(0, 0);
#pragma unroll
    for (int s = 0; s < NSTEPS; ++s) {
        __syncthreads();                       // drains stage(s), all waves synced
        if (s + 1 < NSTEPS) GL_STAGE(s + 1, (s + 1) & 1);
        const int buf = s & 1;
        bf16x8 a[4], b[4];
#pragma unroll
        for (int mi = 0; mi < 4; ++mi)
            a[mi] = *(const bf16x8*)((const char*)As[buf] + ((wm * 4 + mi) << 10) + lane * 16);
#pragma unroll
        for (int j = 0; j < 4; ++j)
            b[j] = *(const bf16x8*)((const char*)Bs[buf] + ((wn * 4 + j) << 10) + lane * 16);
#pragma unroll
        for (int mi = 0; mi < 4; ++mi)
#pragma unroll
            for (int j = 0; j < 4; ++j)
                acc[mi][j] = __builtin_amdgcn_mfma_f32_16x16x32_bf16(a[mi], b[j], acc[mi][j], 0, 0, 0);
    }
#undef GL_STAGE

    // C/D layout: col = lane&15, row = (lane>>4)*4 + reg
    const int cbase = bn + wn * 64 + (lane & 15);
    const int rb = bm + wm * 64 + ((lane >> 4) << 2);
#pragma unroll
    for (int j = 0; j < 4; ++j) {
        const float bj = bias[cbase - bn + bn + j * 16];  // bias[cbase + j*16]
#pragma unroll
        for (int mi = 0; mi < 4; ++mi)
#pragma unroll
            for (int r = 0; r < 4; ++r) {
                const int row = rb + mi * 16 + r;
                if (row < M) {
                    float v = acc[mi][j][r] + bj;
                    if (relu) v = fmaxf(v, 0.f);
                    Cout[(size_t)row * ldc + cbase + j * 16] = f2b(v);
                }
            }
    }
}

// ---------------- fused layer tail, BOTH etypes, LDS-pipelined ----------------
// Block 32 rows x 256 cols, 4 waves (wave 32x64), grid 625 exact.
// 32 K-steps: segs {h@Ws[t0], neigh0@Wn[t0]} -> LN(etype0) -> {h@Ws[t1], neigh1@Wn[t1]}
// -> LN(etype1); out = sum of the two normalized results. acc reused across etypes.
template <int LAST>
__global__ __launch_bounds__(256) void sage_tail_lds(
    const unsigned short* __restrict__ h,      // [N,256] bf16
    const unsigned short* __restrict__ neigh,  // [N,512] bf16 (both etypes)
    const unsigned short* __restrict__ Ws,     // wself_f layer base (t0; t1 at +65536)
    const unsigned short* __restrict__ Wn,     // wneigh_f layer base
    const float* __restrict__ bias, const float* __restrict__ gamma,
    const float* __restrict__ beta, void* __restrict__ outp)
{
    __shared__ __align__(16) unsigned short As[2][1024];  // 2KB per buf (32 rows x 32 k)
    __shared__ __align__(16) unsigned short Bs[2][8192];  // 16KB per buf (256 cols x 32 k)
    __shared__ float sS[4][32], sQ[4][32];
    const int tid = threadIdx.x, lane = tid & 63, w = tid >> 6;   // w = col-wave
    const int bm = blockIdx.x * 32;

    // A staging (only waves 0,1; 128 chunks): c=tid -> subtile mi=c>>6, row, kq
    size_t offH = 0, offN = 0;
    if (tid < 128) {
        const int c = tid, mi = c >> 6, ww = c & 63, r = ww & 15, kq = ww >> 4;
        const int rg = bm + mi * 16 + r;               // 625*32 = 20000 exact
        offH = (size_t)rg * 256 + kq * 8;
        offN = (size_t)rg * 512 + kq * 8;
    }
    // B staging: 1024 chunks; chunk c -> n-slab c>>9 (stride 8 steps x 4096), within c&511
    int offB[4];
#pragma unroll
    for (int q = 0; q < 4; ++q) {
        const int c = q * 256 + tid;
        offB[q] = ((c >> 9) << 15) + ((c & 511) << 3);
    }

    f32x4 acc[2][4] = {};    // [m-subtile][n-tile j]
    f32x4 outv[2][4] = {};

#define TSTAGE(S, BUF) do { \
    const int seg_ = (S) >> 3, ss_ = (S) & 7; \
    if (tid < 128) { \
        const unsigned short* as_ = (seg_ == 0 || seg_ == 2) ? (h + offH) \
                                  : (neigh + (seg_ == 3 ? 256 : 0) + offN); \
        gload16(as_ + ss_ * 32, &As[BUF][w * 512]); \
    } \
    const unsigned short* wb_ = ((seg_ & 1) ? Wn : Ws) + ((seg_ >> 1) * 65536); \
    _Pragma("unroll") \
    for (int q_ = 0; q_ < 4; ++q_) \
        gload16(wb_ + offB[q_] + ss_ * 4096, &Bs[BUF][(q_ * 256 + w * 64) * 8]); \
} while (0)

#define LN_PHASE(E) do { \
    const int colb_ = w * 64 + (lane & 15); \
    const int rq_ = (lane >> 4) << 2; \
    float bia_[4], gam_[4], bet_[4]; \
    _Pragma("unroll") for (int j = 0; j < 4; ++j) { \
        const int col_ = (E) * 256 + colb_ + j * 16; \
        bia_[j] = bias[col_]; gam_[j] = gamma[col_]; bet_[j] = beta[col_]; } \
    _Pragma("unroll") for (int mi = 0; mi < 2; ++mi) \
    _Pragma("unroll") for (int r = 0; r < 4; ++r) { \
        float s_ = 0.f, q_ = 0.f; \
        _Pragma("unroll") for (int j = 0; j < 4; ++j) { \
            float v_ = acc[mi][j][r] + bia_[j]; \
            if (!LAST) v_ = fmaxf(v_, 0.f); \
            s_ += v_; q_ += v_ * v_; } \
        _Pragma("unroll") for (int o_ = 1; o_ < 16; o_ <<= 1) { \
            s_ += __shfl_xor(s_, o_); q_ += __shfl_xor(q_, o_); } \
        if ((lane & 15) == 0) { \
            sS[w][mi * 16 + ((lane >> 4) << 2) + r] = s_; \
            sQ[w][mi * 16 + ((lane >> 4) << 2) + r] = q_; } } \
    __syncthreads(); \
    _Pragma("unroll") for (int mi = 0; mi < 2; ++mi) \
    _Pragma("unroll") for (int r = 0; r < 4; ++r) { \
        const int rl_ = mi * 16 + rq_ + r; \
        const float st_ = sS[0][rl_] + sS[1][rl_] + sS[2][rl_] + sS[3][rl_]; \
        const float qt_ = sQ[0][rl_] + sQ[1][rl_] + sQ[2][rl_] + sQ[3][rl_]; \
        const float mean_ = st_ * (1.f / 256.f); \
        const float var_ = qt_ * (1.f / 256.f) - mean_ * mean_; \
        const float inv_ = rsqrtf(var_ + 1e-5f); \
        _Pragma("unroll") for (int j = 0; j < 4; ++j) { \
            float v_ = acc[mi][j][r] + bia_[j]; \
            if (!LAST) v_ = fmaxf(v_, 0.f); \
            outv[mi][j][r] += (v_ - mean_) * inv_ * gam_[j] + bet_[j]; \
            acc[mi][j][r] = 0.f; } } \
} while (0)

    TSTAGE(0, 0);
#pragma unroll
    for (int s = 0; s < 32; ++s) {
        __syncthreads();                     // drains stage(s)
        if (s == 16) LN_PHASE(0);            // etype0 done after steps 0..15
        if (s + 1 < 32) TSTAGE(s + 1, (s + 1) & 1);
        const int buf = s & 1;
        bf16x8 a[2], b[4];
        a[0] = *(const bf16x8*)((const char*)As[buf] + lane * 16);
        a[1] = *(const bf16x8*)((const char*)As[buf] + 1024 + lane * 16);
#pragma unroll
        for (int j = 0; j < 4; ++j) {
            const int t = w * 4 + j;         // tiles 0..15 over 2 n-slabs
            b[j] = *(const bf16x8*)((const char*)Bs[buf] + ((t >> 3) << 13) + ((t & 7) << 10) + lane * 16);
        }
#pragma unroll
        for (int mi = 0; mi < 2; ++mi)
#pragma unroll
            for (int j = 0; j < 4; ++j)
                acc[mi][j] = __builtin_amdgcn_mfma_f32_16x16x32_bf16(a[mi], b[j], acc[mi][j], 0, 0, 0);
    }
    LN_PHASE(1);
#undef TSTAGE
#undef LN_PHASE

    // store summed, per-etype-normalized result
    const int colb = w * 64 + (lane & 15);
    const int rq = (lane >> 4) << 2;
#pragma unroll
    for (int mi = 0; mi < 2; ++mi)
#pragma unroll
        for (int r = 0; r < 4; ++r) {
            const int row = bm + mi * 16 + rq + r;
#pragma unroll
            for (int j = 0; j < 4; ++j) {
                const int col = colb + j * 16;
                if (LAST) ((float*)outp)[(size_t)row * D_H + col] = outv[mi][j][r];
                else ((unsigned short*)outp)[(size_t)row * D_H + col] = f2b(outv[mi][j][r]);
            }
        }
}

// ---------------- CSR build (both etypes batched; once per launch) ----------------
__global__ __launch_bounds__(256) void zero_int_kernel(int* p, int n)
{
    int i = blockIdx.x * 256 + threadIdx.x;
    if (i < n) p[i] = 0;
}

__global__ __launch_bounds__(256) void count_deg_kernel(
    const int* __restrict__ dst, int* __restrict__ cnt, int E2)
{
    int e = blockIdx.x * 256 + threadIdx.x;
    if (e < E2) {
        const int base = (e >= E_EDGES) ? N_NODES : 0;
        atomicAdd(&cnt[base + dst[e]], 1);
    }
}

__global__ __launch_bounds__(256) void scanA_kernel(
    const int* __restrict__ cnt, int* __restrict__ incl, int* __restrict__ bsum, int n)
{
    __shared__ int tmp[256];
    const int tid = threadIdx.x;
    const int i = blockIdx.x * 256 + tid;
    const int v = (i < n) ? cnt[i] : 0;
    tmp[tid] = v;
    __syncthreads();
#pragma unroll
    for (int o = 1; o < 256; o <<= 1) {
        const int t = (tid >= o) ? tmp[tid - o] : 0;
        __syncthreads();
        tmp[tid] += t;
        __syncthreads();
    }
    if (i < n) incl[i] = tmp[tid];
    if (tid == 255) bsum[blockIdx.x] = tmp[255];
}

__global__ __launch_bounds__(256) void scanB_kernel(int* __restrict__ bsum, int nb)
{
    __shared__ int tmp[256];
    const int tid = threadIdx.x;
    const int v = (tid < nb) ? bsum[tid] : 0;
    tmp[tid] = v;
    __syncthreads();
#pragma unroll
    for (int o = 1; o < 256; o <<= 1) {
        const int t = (tid >= o) ? tmp[tid - o] : 0;
        __syncthreads();
        tmp[tid] += t;
        __syncthreads();
    }
    if (tid < nb) bsum[tid] = tmp[tid] - v;  // exclusive
}

__global__ __launch_bounds__(256) void scanC_kernel(
    const int* __restrict__ cnt, const int* __restrict__ incl,
    const int* __restrict__ bsum, int* __restrict__ off, int* __restrict__ cursor, int n)
{
    const int i = blockIdx.x * 256 + threadIdx.x;
    if (i < n) {
        const int e = incl[i] + bsum[blockIdx.x];
        off[i + 1] = e;
        cursor[i] = e - cnt[i];
    }
    if (i == 0) off[0] = 0;
}

__global__ __launch_bounds__(256) void fill_csr_kernel(
    const int* __restrict__ src, const int* __restrict__ dst,
    int* __restrict__ cursor, int* __restrict__ esrc, int E2)
{
    int e = blockIdx.x * 256 + threadIdx.x;
    if (e < E2) {
        const int base = (e >= E_EDGES) ? N_NODES : 0;
        const int pos = atomicAdd(&cursor[base + dst[e]], 1);
        esrc[pos] = src[e];
    }
}

// ---------------- segment max (bf16, both etypes): one wave per (node,t) ----------------
__device__ __forceinline__ ushort4 umax4(ushort4 a, ushort4 b)
{
    a.x = a.x > b.x ? a.x : b.x;
    a.y = a.y > b.y ? a.y : b.y;
    a.z = a.z > b.z ? a.z : b.z;
    a.w = a.w > b.w ? a.w : b.w;
    return a;
}

__global__ __launch_bounds__(256) void seg_max_kernel(
    const unsigned short* __restrict__ hp, const int* __restrict__ off,
    const int* __restrict__ esrc, unsigned short* __restrict__ neigh)
{
    const int g = blockIdx.x * 4 + (threadIdx.x >> 6);
    if (g >= 2 * N_NODES) return;
    const int t = (g >= N_NODES) ? 1 : 0;
    const int node = g - t * N_NODES;
    const int lane = threadIdx.x & 63;
    const int co = t * D_H + lane * 4;
    const int e0 = off[g], e1 = off[g + 1];
    ushort4 acc = make_ushort4(0, 0, 0, 0);
    int e = e0;
    for (; e + 4 <= e1; e += 4) {
        const int s0 = esrc[e + 0], s1 = esrc[e + 1];
        const int s2 = esrc[e + 2], s3 = esrc[e + 3];
        const ushort4 v0 = *(const ushort4*)(hp + (size_t)s0 * 512 + co);
        const ushort4 v1 = *(const ushort4*)(hp + (size_t)s1 * 512 + co);
        const ushort4 v2 = *(const ushort4*)(hp + (size_t)s2 * 512 + co);
        const ushort4 v3 = *(const ushort4*)(hp + (size_t)s3 * 512 + co);
        acc = umax4(umax4(umax4(acc, v0), umax4(v1, v2)), v3);
    }
    for (; e < e1; ++e)
        acc = umax4(acc, *(const ushort4*)(hp + (size_t)esrc[e] * 512 + co));
    *(ushort4*)(neigh + (size_t)node * 512 + co) = acc;
}

extern "C" void kernel_launch(void* const* d_in, const int* in_sizes, int n_in,
                              void* d_out, int out_size, void* d_ws, size_t ws_size,
                              hipStream_t stream)
{
    const float* x      = (const float*)d_in[0];
    const int*   src    = (const int*)d_in[1];
    const int*   dst    = (const int*)d_in[2];
    const float* Wlin   = (const float*)d_in[3];
    const float* blin   = (const float*)d_in[4];
    const float* Wpool  = (const float*)d_in[5];
    const float* bpool  = (const float*)d_in[6];
    const float* Wself  = (const float*)d_in[7];
    const float* Wneigh = (const float*)d_in[8];
    const float* bconv  = (const float*)d_in[9];
    const float* gamma  = (const float*)d_in[10];
    const float* beta   = (const float*)d_in[11];

    const size_t NB = (size_t)N_NODES * D_H;  // 5.12M
    char* p = (char*)d_ws;
    unsigned short* hp_b    = (unsigned short*)p; p += NB * 2 * T_ETYPES;  // [N,512]
    unsigned short* neigh_b = (unsigned short*)p; p += NB * 2 * T_ETYPES;  // [N,512]
    unsigned short* h_a     = (unsigned short*)p; p += NB * 2;
    unsigned short* h_b     = (unsigned short*)p; p += NB * 2;
    unsigned short* xb      = (unsigned short*)p; p += (size_t)N_NODES * F_IN * 2;  // 20.48MB
    unsigned short* wlin_f  = (unsigned short*)p; p += (size_t)D_H * F_IN * 2;
    const size_t WSZ = (size_t)L_LAYERS * T_ETYPES * D_H * D_H;  // 393216
    unsigned short* wpool_f = (unsigned short*)p; p += WSZ * 2;
    unsigned short* wself_f = (unsigned short*)p; p += WSZ * 2;
    unsigned short* wneigh_f= (unsigned short*)p; p += WSZ * 2;
    int* ip = (int*)p;
    const int NT = T_ETYPES * N_NODES;  // 40000
    int* cnt    = ip; ip += NT;
    int* incl   = ip; ip += NT;
    int* off    = ip; ip += NT + 1;
    int* cursor = ip; ip += NT;
    int* esrc   = ip; ip += T_ETYPES * E_EDGES;
    int* bsum   = ip; ip += 256;

    const dim3 blk(256);
    const int E2 = T_ETYPES * E_EDGES;
    const dim3 e2grid((E2 + 255) / 256);
    const dim3 ntgrid((NT + 255) / 256);
    const int nScanBlk = (NT + 255) / 256;  // 157

    // ---- weights -> bf16 fragment-slab order (one dispatch) ----
    {
        const int nlin = D_H * F_IN;          // 131072, NO=256 K=512
        const int nw   = (int)WSZ;            // 393216
        const int tot  = nlin + 3 * nw;
        shufw_kernel<<<dim3((tot + 255) / 256), blk, 0, stream>>>(
            Wlin, wlin_f, D_H, F_IN, nlin,
            Wpool, wpool_f, T_ETYPES * D_H, D_H, nw,   // per layer: [512,256]
            Wself, wself_f, D_H, D_H, nw,              // per (l,t): [256,256]
            Wneigh, wneigh_f, D_H, D_H, nw);
    }

    // ---- x -> bf16 (once) ----
    cvt_bf16_kernel<<<dim3((N_NODES * F_IN / 8 + 255) / 256), blk, 0, stream>>>(
        x, xb, N_NODES * F_IN / 8);

    // ---- CSR build, both etypes batched ----
    zero_int_kernel<<<ntgrid, blk, 0, stream>>>(cnt, NT);
    count_deg_kernel<<<e2grid, blk, 0, stream>>>(dst, cnt, E2);
    scanA_kernel<<<dim3(nScanBlk), blk, 0, stream>>>(cnt, incl, bsum, NT);
    scanB_kernel<<<dim3(1), blk, 0, stream>>>(bsum, nScanBlk);
    scanC_kernel<<<dim3(nScanBlk), blk, 0, stream>>>(cnt, incl, bsum, off, cursor, NT);
    fill_csr_kernel<<<e2grid, blk, 0, stream>>>(src, dst, cursor, esrc, E2);

    const int MB = (N_NODES + 127) / 128;  // 157

    // ---- h0 = bf16(xb @ Wlin^T + blin), K=512 ----
    gemm_lds<16><<<dim3(2, MB), blk, 0, stream>>>(
        xb, wlin_f, blin, h_a, N_NODES, D_H, 0);

    unsigned short* h = h_a;
    unsigned short* hn = h_b;
    const dim3 sgrid((2 * N_NODES + 3) / 4);
    const dim3 fgrid(N_NODES / 32);             // 625, exact
    for (int l = 0; l < L_LAYERS; ++l) {
        // hp[:, t*256:] = bf16(relu(h @ Wpool[l,t]^T + bpool[l,t])), both t in one dispatch
        gemm_lds<8><<<dim3(4, MB), blk, 0, stream>>>(
            h, wpool_f + (size_t)l * T_ETYPES * D_H * D_H,
            bpool + (size_t)l * T_ETYPES * D_H, hp_b, N_NODES, T_ETYPES * D_H, 1);
        // neigh = segment_max per (node, t)
        seg_max_kernel<<<sgrid, blk, 0, stream>>>(hp_b, off, esrc, neigh_b);
        // fused tail, BOTH etypes, LDS-pipelined
        const size_t wlo = (size_t)l * T_ETYPES * D_H * D_H;
        const size_t blo = (size_t)l * T_ETYPES * D_H;
        if (l < L_LAYERS - 1) {
            sage_tail_lds<0><<<fgrid, blk, 0, stream>>>(
                h, neigh_b, wself_f + wlo, wneigh_f + wlo,
                bconv + blo, gamma + blo, beta + blo, hn);
        } else {
            sage_tail_lds<1><<<fgrid, blk, 0, stream>>>(
                h, neigh_b, wself_f + wlo, wneigh_f + wlo,
                bconv + blo, gamma + blo, beta + blo, d_out);
        }
        unsigned short* tmp = h; h = hn; hn = tmp;
    }
}

// Round 3
// 459.208 us; speedup vs baseline: 1.1374x; 1.0407x over previous
//
#include <hip/hip_runtime.h>

// Problem constants (from reference)
#define N_NODES 20000
#define F_IN    512
#define D_H     256
#define E_EDGES 200000
#define L_LAYERS 3
#define T_ETYPES 2

typedef __attribute__((ext_vector_type(8))) short bf16x8;
typedef __attribute__((ext_vector_type(4))) float f32x4;

__device__ __forceinline__ unsigned short f2b(float f) {
    unsigned int u = __float_as_uint(f);
    u = (u + 0x7FFFu + ((u >> 16) & 1u)) >> 16;   // round-nearest-even
    return (unsigned short)u;
}
__device__ __forceinline__ unsigned int pack2(float a, float b) {
    return (unsigned int)f2b(a) | ((unsigned int)f2b(b) << 16);
}

// async global->LDS, 16B per lane; LDS dest = wave-uniform base + lane*16,
// global source is per-lane (this is how we deposit fragment-slab order).
__device__ __forceinline__ void gload16(const unsigned short* g, unsigned short* l)
{
    __builtin_amdgcn_global_load_lds(
        (const __attribute__((address_space(1))) void*)g,
        (__attribute__((address_space(3))) void*)l, 16, 0, 0);
}

// ---------------- weight pre-shuffle: fp32 row-major -> bf16 fragment-slab order ----
// For W[NO,K]: slab (n>>7, k>>5) of 128 rows x 32 k is a contiguous 4096-elem (8KB) block;
// inside, elem (n_local,kk) at ((n_local>>4)&7)<<9 | ((kk>>3)&3)<<7 | (n_local&15)<<3 | (kk&7)
// i.e. 8 subtiles of 16 rows x 32 k, each a 1KB lane-major MFMA fragment run.
__device__ __forceinline__ void shuf_one(const float* s, unsigned short* d,
                                         int NO, int K, int i)
{
    const int matsz = NO * K;
    const int mat = i / matsz;
    const int rem = i - mat * matsz;
    const int n = rem / K;
    const int k = rem - n * K;
    const int dst = mat * matsz + ((n >> 7) * (K >> 5) + (k >> 5)) * 4096
                  + (((n >> 4) & 7) << 9) + (((k >> 3) & 3) << 7)
                  + ((n & 15) << 3) + (k & 7);
    d[dst] = f2b(s[i]);
}

__global__ __launch_bounds__(256) void shufw_kernel(
    const float* __restrict__ s0, unsigned short* __restrict__ d0, int NO0, int K0, int n0,
    const float* __restrict__ s1, unsigned short* __restrict__ d1, int NO1, int K1, int n1,
    const float* __restrict__ s2, unsigned short* __restrict__ d2, int NO2, int K2, int n2,
    const float* __restrict__ s3, unsigned short* __restrict__ d3, int NO3, int K3, int n3)
{
    int i = blockIdx.x * 256 + threadIdx.x;
    if (i < n0) { shuf_one(s0, d0, NO0, K0, i); return; }
    if ((i -= n0) < n1) { shuf_one(s1, d1, NO1, K1, i); return; }
    if ((i -= n1) < n2) { shuf_one(s2, d2, NO2, K2, i); return; }
    if ((i -= n2) < n3) { shuf_one(s3, d3, NO3, K3, i); return; }
}

// ---------------- x fp32 -> bf16 (once) ----------------
__global__ __launch_bounds__(256) void cvt_bf16_kernel(
    const float* __restrict__ in, unsigned short* __restrict__ out, int n8)
{
    const int i = blockIdx.x * 256 + threadIdx.x;
    if (i < n8) {
        const float4 a = ((const float4*)in)[i * 2];
        const float4 b = ((const float4*)in)[i * 2 + 1];
        uint4 u;
        u.x = pack2(a.x, a.y); u.y = pack2(a.z, a.w);
        u.z = pack2(b.x, b.y); u.w = pack2(b.z, b.w);
        ((uint4*)out)[i] = u;
    }
}

// ---------------- m97-style GEMM: LDS double-buffer + global_load_lds ----------------
// C[M, bn:bn+128] = act(A @ W^T + bias). Block 128x128, 4 waves 2x2, wave 64x64.
// A-tile staged into fragment-slab order (8 subtiles x 1KB) via per-lane source addrs;
// B-tile is a verbatim copy of the pre-shuffled weight slab. All ds_reads are
// lane-contiguous 1KB ds_read_b128 runs: conflict-free by construction.
template <int NSTEPS>
__global__ __launch_bounds__(256) void gemm_lds(
    const unsigned short* __restrict__ A,   // [M, K] bf16, K = NSTEPS*32
    const unsigned short* __restrict__ Wf,  // fragment-slab weights, col-slab = blockIdx.x
    const float* __restrict__ bias, unsigned short* __restrict__ Cout,
    int M, int ldc, int relu)
{
    __shared__ __align__(16) unsigned short As[2][4096];  // 8KB per buf
    __shared__ __align__(16) unsigned short Bs[2][4096];
    const int K = NSTEPS * 32;
    const int tid = threadIdx.x, lane = tid & 63, w = tid >> 6;
    const int wm = w >> 1, wn = w & 1;
    const int bm = blockIdx.y * 128, bn = blockIdx.x * 128;
    const unsigned short* slab0 = Wf + (((size_t)blockIdx.x * NSTEPS) << 12);

    // A staging source precompute: chunk c = q*256+tid carries subtile mi=c>>6,
    // row r=(c&63)&15, k-quarter kq=(c&63)>>4 -> per-lane global offset (shorts).
    size_t aoff[2];
#pragma unroll
    for (int q = 0; q < 2; ++q) {
        const int c = q * 256 + tid;
        const int mi = c >> 6, ww = c & 63, r = ww & 15, kq = ww >> 4;
        const int rg = min(bm + mi * 16 + r, M - 1);
        aoff[q] = (size_t)rg * K + kq * 8;
    }

    f32x4 acc[4][4] = {};

#define GL_STAGE(S, BUF) do { \
    _Pragma("unroll") \
    for (int q_ = 0; q_ < 2; ++q_) { \
        gload16(A + aoff[q_] + (S) * 32, &As[BUF][(q_ * 256 + w * 64) * 8]); \
        gload16(slab0 + (((size_t)(S)) << 12) + (size_t)(q_ * 256 + tid) * 8, \
                &Bs[BUF][(q_ * 256 + w * 64) * 8]); \
    } \
} while (0)

    GL_STAGE(0, 0);
#pragma unroll
    for (int s = 0; s < NSTEPS; ++s) {
        __syncthreads();                       // drains stage(s), all waves synced
        if (s + 1 < NSTEPS) GL_STAGE(s + 1, (s + 1) & 1);
        const int buf = s & 1;
        bf16x8 a[4], b[4];
#pragma unroll
        for (int mi = 0; mi < 4; ++mi)
            a[mi] = *(const bf16x8*)((const char*)As[buf] + ((wm * 4 + mi) << 10) + lane * 16);
#pragma unroll
        for (int j = 0; j < 4; ++j)
            b[j] = *(const bf16x8*)((const char*)Bs[buf] + ((wn * 4 + j) << 10) + lane * 16);
#pragma unroll
        for (int mi = 0; mi < 4; ++mi)
#pragma unroll
            for (int j = 0; j < 4; ++j)
                acc[mi][j] = __builtin_amdgcn_mfma_f32_16x16x32_bf16(a[mi], b[j], acc[mi][j], 0, 0, 0);
    }
#undef GL_STAGE

    // C/D layout: col = lane&15, row = (lane>>4)*4 + reg
    const int cbase = bn + wn * 64 + (lane & 15);
    const int rb = bm + wm * 64 + ((lane >> 4) << 2);
#pragma unroll
    for (int j = 0; j < 4; ++j) {
        const float bj = bias[cbase + j * 16];
#pragma unroll
        for (int mi = 0; mi < 4; ++mi)
#pragma unroll
            for (int r = 0; r < 4; ++r) {
                const int row = rb + mi * 16 + r;
                if (row < M) {
                    float v = acc[mi][j][r] + bj;
                    if (relu) v = fmaxf(v, 0.f);
                    Cout[(size_t)row * ldc + cbase + j * 16] = f2b(v);
                }
            }
    }
}

// ---------------- tail GEMM: R[N,512] = relu?(h@Ws[e]^T + neigh_e@Wn[e]^T + b) ------
// Same 128x128-block m97 structure as gemm_lds; K=512 streamed from two A sources
// (steps 0..7: h, steps 8..15: neigh slice for etype e = col-slab>>1). fp32 output.
template <int RELU>
__global__ __launch_bounds__(256) void tail_gemm(
    const unsigned short* __restrict__ h,      // [N,256] bf16
    const unsigned short* __restrict__ neigh,  // [N,512] bf16 (both etypes)
    const unsigned short* __restrict__ Ws,     // wself_f layer base (t0; t1 at +65536)
    const unsigned short* __restrict__ Wn,     // wneigh_f layer base
    const float* __restrict__ bias,            // [512] layer base
    float* __restrict__ R)                     // [N,512] fp32
{
    __shared__ __align__(16) unsigned short As[2][4096];
    __shared__ __align__(16) unsigned short Bs[2][4096];
    const int tid = threadIdx.x, lane = tid & 63, w = tid >> 6;
    const int wm = w >> 1, wn = w & 1;
    const int bm = blockIdx.y * 128;
    const int cs = blockIdx.x;                 // col-slab 0..3
    const int e  = cs >> 1;
    const unsigned short* Bself  = Ws + (size_t)e * 65536 + (cs & 1) * 32768;
    const unsigned short* Bneigh = Wn + (size_t)e * 65536 + (cs & 1) * 32768;

    size_t aoffH[2], aoffN[2];
#pragma unroll
    for (int q = 0; q < 2; ++q) {
        const int c = q * 256 + tid;
        const int mi = c >> 6, ww = c & 63, r = ww & 15, kq = ww >> 4;
        const int rg = min(bm + mi * 16 + r, N_NODES - 1);
        aoffH[q] = (size_t)rg * 256 + kq * 8;
        aoffN[q] = (size_t)rg * 512 + e * 256 + kq * 8;
    }

    f32x4 acc[4][4] = {};

#define TG_STAGE(S, BUF) do { \
    _Pragma("unroll") \
    for (int q_ = 0; q_ < 2; ++q_) { \
        const unsigned short* as_ = ((S) < 8) ? (h + aoffH[q_] + (S) * 32) \
                                              : (neigh + aoffN[q_] + ((S) - 8) * 32); \
        gload16(as_, &As[BUF][(q_ * 256 + w * 64) * 8]); \
        const unsigned short* bs_ = (((S) < 8) ? (Bself + (S) * 4096) \
                                               : (Bneigh + ((S) - 8) * 4096)) \
                                    + (size_t)(q_ * 256 + tid) * 8; \
        gload16(bs_, &Bs[BUF][(q_ * 256 + w * 64) * 8]); \
    } \
} while (0)

    TG_STAGE(0, 0);
#pragma unroll
    for (int s = 0; s < 16; ++s) {
        __syncthreads();                       // drains stage(s)
        if (s + 1 < 16) TG_STAGE(s + 1, (s + 1) & 1);
        const int buf = s & 1;
        bf16x8 a[4], b[4];
#pragma unroll
        for (int mi = 0; mi < 4; ++mi)
            a[mi] = *(const bf16x8*)((const char*)As[buf] + ((wm * 4 + mi) << 10) + lane * 16);
#pragma unroll
        for (int j = 0; j < 4; ++j)
            b[j] = *(const bf16x8*)((const char*)Bs[buf] + ((wn * 4 + j) << 10) + lane * 16);
#pragma unroll
        for (int mi = 0; mi < 4; ++mi)
#pragma unroll
            for (int j = 0; j < 4; ++j)
                acc[mi][j] = __builtin_amdgcn_mfma_f32_16x16x32_bf16(a[mi], b[j], acc[mi][j], 0, 0, 0);
    }
#undef TG_STAGE

    const int cbase = cs * 128 + wn * 64 + (lane & 15);
    const int rb = bm + wm * 64 + ((lane >> 4) << 2);
#pragma unroll
    for (int j = 0; j < 4; ++j) {
        const float bj = bias[cbase + j * 16];
#pragma unroll
        for (int mi = 0; mi < 4; ++mi)
#pragma unroll
            for (int r = 0; r < 4; ++r) {
                const int row = rb + mi * 16 + r;
                if (row < N_NODES) {
                    float v = acc[mi][j][r] + bj;
                    if (RELU) v = fmaxf(v, 0.f);
                    R[(size_t)row * 512 + cbase + j * 16] = v;
                }
            }
    }
}

// ---------------- LN + etype-sum: out[r] = LN0(R[r,0:256]) + LN1(R[r,256:512]) ------
// One wave per row; memory-bound (41MB read, 10-20MB write).
template <int LAST>
__global__ __launch_bounds__(256) void ln_sum_kernel(
    const float* __restrict__ R,               // [N,512] fp32 (relu already applied)
    const float* __restrict__ gamma,           // [512] layer base
    const float* __restrict__ beta,
    void* __restrict__ outp)                   // bf16 [N,256] or fp32 [N,256]
{
    const int row  = blockIdx.x * 4 + (threadIdx.x >> 6);
    const int lane = threadIdx.x & 63;
    const float4 v0 = ((const float4*)R)[(size_t)row * 128 + lane];
    const float4 v1 = ((const float4*)R)[(size_t)row * 128 + 64 + lane];
    float s0 = v0.x + v0.y + v0.z + v0.w;
    float q0 = v0.x * v0.x + v0.y * v0.y + v0.z * v0.z + v0.w * v0.w;
    float s1 = v1.x + v1.y + v1.z + v1.w;
    float q1 = v1.x * v1.x + v1.y * v1.y + v1.z * v1.z + v1.w * v1.w;
#pragma unroll
    for (int o = 1; o < 64; o <<= 1) {
        s0 += __shfl_xor(s0, o); q0 += __shfl_xor(q0, o);
        s1 += __shfl_xor(s1, o); q1 += __shfl_xor(q1, o);
    }
    const float m0 = s0 * (1.f / 256.f), m1 = s1 * (1.f / 256.f);
    const float i0 = rsqrtf(q0 * (1.f / 256.f) - m0 * m0 + 1e-5f);
    const float i1 = rsqrtf(q1 * (1.f / 256.f) - m1 * m1 + 1e-5f);
    const float4 g0 = ((const float4*)gamma)[lane];
    const float4 b0 = ((const float4*)beta)[lane];
    const float4 g1 = ((const float4*)(gamma + 256))[lane];
    const float4 b1 = ((const float4*)(beta + 256))[lane];
    const float o0 = (v0.x - m0) * i0 * g0.x + b0.x + (v1.x - m1) * i1 * g1.x + b1.x;
    const float o1 = (v0.y - m0) * i0 * g0.y + b0.y + (v1.y - m1) * i1 * g1.y + b1.y;
    const float o2 = (v0.z - m0) * i0 * g0.z + b0.z + (v1.z - m1) * i1 * g1.z + b1.z;
    const float o3 = (v0.w - m0) * i0 * g0.w + b0.w + (v1.w - m1) * i1 * g1.w + b1.w;
    if (LAST) {
        ((float4*)outp)[(size_t)row * 64 + lane] = make_float4(o0, o1, o2, o3);
    } else {
        ushort4 u;
        u.x = f2b(o0); u.y = f2b(o1); u.z = f2b(o2); u.w = f2b(o3);
        ((ushort4*)outp)[(size_t)row * 64 + lane] = u;
    }
}

// ---------------- CSR build (both etypes batched; once per launch) ----------------
__global__ __launch_bounds__(256) void count_deg_kernel(
    const int* __restrict__ dst, int* __restrict__ cnt, int E2)
{
    int e = blockIdx.x * 256 + threadIdx.x;
    if (e < E2) {
        const int base = (e >= E_EDGES) ? N_NODES : 0;
        atomicAdd(&cnt[base + dst[e]], 1);
    }
}

__global__ __launch_bounds__(256) void scanA_kernel(
    const int* __restrict__ cnt, int* __restrict__ incl, int* __restrict__ bsum, int n)
{
    __shared__ int tmp[256];
    const int tid = threadIdx.x;
    const int i = blockIdx.x * 256 + tid;
    const int v = (i < n) ? cnt[i] : 0;
    tmp[tid] = v;
    __syncthreads();
#pragma unroll
    for (int o = 1; o < 256; o <<= 1) {
        const int t = (tid >= o) ? tmp[tid - o] : 0;
        __syncthreads();
        tmp[tid] += t;
        __syncthreads();
    }
    if (i < n) incl[i] = tmp[tid];
    if (tid == 255) bsum[blockIdx.x] = tmp[255];
}

__global__ __launch_bounds__(256) void scanB_kernel(int* __restrict__ bsum, int nb)
{
    __shared__ int tmp[256];
    const int tid = threadIdx.x;
    const int v = (tid < nb) ? bsum[tid] : 0;
    tmp[tid] = v;
    __syncthreads();
#pragma unroll
    for (int o = 1; o < 256; o <<= 1) {
        const int t = (tid >= o) ? tmp[tid - o] : 0;
        __syncthreads();
        tmp[tid] += t;
        __syncthreads();
    }
    if (tid < nb) bsum[tid] = tmp[tid] - v;  // exclusive
}

__global__ __launch_bounds__(256) void scanC_kernel(
    const int* __restrict__ cnt, const int* __restrict__ incl,
    const int* __restrict__ bsum, int* __restrict__ off, int* __restrict__ cursor, int n)
{
    const int i = blockIdx.x * 256 + threadIdx.x;
    if (i < n) {
        const int e = incl[i] + bsum[blockIdx.x];
        off[i + 1] = e;
        cursor[i] = e - cnt[i];
    }
    if (i == 0) off[0] = 0;
}

__global__ __launch_bounds__(256) void fill_csr_kernel(
    const int* __restrict__ src, const int* __restrict__ dst,
    int* __restrict__ cursor, int* __restrict__ esrc, int E2)
{
    int e = blockIdx.x * 256 + threadIdx.x;
    if (e < E2) {
        const int base = (e >= E_EDGES) ? N_NODES : 0;
        const int pos = atomicAdd(&cursor[base + dst[e]], 1);
        esrc[pos] = src[e];
    }
}

// ---------------- segment max (bf16, both etypes): one wave per (node,t) ----------------
__device__ __forceinline__ ushort4 umax4(ushort4 a, ushort4 b)
{
    a.x = a.x > b.x ? a.x : b.x;
    a.y = a.y > b.y ? a.y : b.y;
    a.z = a.z > b.z ? a.z : b.z;
    a.w = a.w > b.w ? a.w : b.w;
    return a;
}

__global__ __launch_bounds__(256) void seg_max_kernel(
    const unsigned short* __restrict__ hp, const int* __restrict__ off,
    const int* __restrict__ esrc, unsigned short* __restrict__ neigh)
{
    const int g = blockIdx.x * 4 + (threadIdx.x >> 6);
    if (g >= 2 * N_NODES) return;
    const int t = (g >= N_NODES) ? 1 : 0;
    const int node = g - t * N_NODES;
    const int lane = threadIdx.x & 63;
    const int co = t * D_H + lane * 4;
    const int e0 = off[g], e1 = off[g + 1];
    ushort4 acc = make_ushort4(0, 0, 0, 0);
    int e = e0;
    for (; e + 4 <= e1; e += 4) {
        const int s0 = esrc[e + 0], s1 = esrc[e + 1];
        const int s2 = esrc[e + 2], s3 = esrc[e + 3];
        const ushort4 v0 = *(const ushort4*)(hp + (size_t)s0 * 512 + co);
        const ushort4 v1 = *(const ushort4*)(hp + (size_t)s1 * 512 + co);
        const ushort4 v2 = *(const ushort4*)(hp + (size_t)s2 * 512 + co);
        const ushort4 v3 = *(const ushort4*)(hp + (size_t)s3 * 512 + co);
        acc = umax4(umax4(umax4(acc, v0), umax4(v1, v2)), v3);
    }
    for (; e < e1; ++e)
        acc = umax4(acc, *(const ushort4*)(hp + (size_t)esrc[e] * 512 + co));
    *(ushort4*)(neigh + (size_t)node * 512 + co) = acc;
}

extern "C" void kernel_launch(void* const* d_in, const int* in_sizes, int n_in,
                              void* d_out, int out_size, void* d_ws, size_t ws_size,
                              hipStream_t stream)
{
    const float* x      = (const float*)d_in[0];
    const int*   src    = (const int*)d_in[1];
    const int*   dst    = (const int*)d_in[2];
    const float* Wlin   = (const float*)d_in[3];
    const float* blin   = (const float*)d_in[4];
    const float* Wpool  = (const float*)d_in[5];
    const float* bpool  = (const float*)d_in[6];
    const float* Wself  = (const float*)d_in[7];
    const float* Wneigh = (const float*)d_in[8];
    const float* bconv  = (const float*)d_in[9];
    const float* gamma  = (const float*)d_in[10];
    const float* beta   = (const float*)d_in[11];

    const size_t NB = (size_t)N_NODES * D_H;  // 5.12M
    char* p = (char*)d_ws;
    unsigned short* hp_b    = (unsigned short*)p; p += NB * 2 * T_ETYPES;  // [N,512]
    unsigned short* neigh_b = (unsigned short*)p; p += NB * 2 * T_ETYPES;  // [N,512]
    unsigned short* h_a     = (unsigned short*)p; p += NB * 2;
    unsigned short* h_b     = (unsigned short*)p; p += NB * 2;
    unsigned short* xb      = (unsigned short*)p; p += (size_t)N_NODES * F_IN * 2;  // 20.48MB
    float*          Rbuf    = (float*)p;          p += (size_t)N_NODES * 512 * 4;   // 40.96MB
    unsigned short* wlin_f  = (unsigned short*)p; p += (size_t)D_H * F_IN * 2;
    const size_t WSZ = (size_t)L_LAYERS * T_ETYPES * D_H * D_H;  // 393216
    unsigned short* wpool_f = (unsigned short*)p; p += WSZ * 2;
    unsigned short* wself_f = (unsigned short*)p; p += WSZ * 2;
    unsigned short* wneigh_f= (unsigned short*)p; p += WSZ * 2;
    int* ip = (int*)p;
    const int NT = T_ETYPES * N_NODES;  // 40000
    int* cnt    = ip; ip += NT;
    int* incl   = ip; ip += NT;
    int* off    = ip; ip += NT + 1;
    int* cursor = ip; ip += NT;
    int* esrc   = ip; ip += T_ETYPES * E_EDGES;
    int* bsum   = ip; ip += 256;

    const dim3 blk(256);
    const int E2 = T_ETYPES * E_EDGES;
    const dim3 e2grid((E2 + 255) / 256);
    const int nScanBlk = (NT + 255) / 256;  // 157

    // ---- weights -> bf16 fragment-slab order (one dispatch) ----
    {
        const int nlin = D_H * F_IN;          // 131072, NO=256 K=512
        const int nw   = (int)WSZ;            // 393216
        const int tot  = nlin + 3 * nw;
        shufw_kernel<<<dim3((tot + 255) / 256), blk, 0, stream>>>(
            Wlin, wlin_f, D_H, F_IN, nlin,
            Wpool, wpool_f, T_ETYPES * D_H, D_H, nw,   // per layer: [512,256]
            Wself, wself_f, D_H, D_H, nw,              // per (l,t): [256,256]
            Wneigh, wneigh_f, D_H, D_H, nw);
    }

    // ---- x -> bf16 (once) ----
    cvt_bf16_kernel<<<dim3((N_NODES * F_IN / 8 + 255) / 256), blk, 0, stream>>>(
        x, xb, N_NODES * F_IN / 8);

    // ---- CSR build, both etypes batched ----
    hipMemsetAsync(cnt, 0, (size_t)NT * sizeof(int), stream);
    count_deg_kernel<<<e2grid, blk, 0, stream>>>(dst, cnt, E2);
    scanA_kernel<<<dim3(nScanBlk), blk, 0, stream>>>(cnt, incl, bsum, NT);
    scanB_kernel<<<dim3(1), blk, 0, stream>>>(bsum, nScanBlk);
    scanC_kernel<<<dim3(nScanBlk), blk, 0, stream>>>(cnt, incl, bsum, off, cursor, NT);
    fill_csr_kernel<<<e2grid, blk, 0, stream>>>(src, dst, cursor, esrc, E2);

    const int MB = (N_NODES + 127) / 128;  // 157

    // ---- h0 = bf16(xb @ Wlin^T + blin), K=512 ----
    gemm_lds<16><<<dim3(2, MB), blk, 0, stream>>>(
        xb, wlin_f, blin, h_a, N_NODES, D_H, 0);

    unsigned short* h = h_a;
    unsigned short* hn = h_b;
    const dim3 sgrid((2 * N_NODES + 3) / 4);
    const dim3 lngrid(N_NODES / 4);             // 5000, exact
    for (int l = 0; l < L_LAYERS; ++l) {
        // hp[:, t*256:] = bf16(relu(h @ Wpool[l,t]^T + bpool[l,t])), both t in one dispatch
        gemm_lds<8><<<dim3(4, MB), blk, 0, stream>>>(
            h, wpool_f + (size_t)l * T_ETYPES * D_H * D_H,
            bpool + (size_t)l * T_ETYPES * D_H, hp_b, N_NODES, T_ETYPES * D_H, 1);
        // neigh = segment_max per (node, t)
        seg_max_kernel<<<sgrid, blk, 0, stream>>>(hp_b, off, esrc, neigh_b);
        // tail GEMM -> R fp32 (relu'd, bias'd), then LN+sum
        const size_t wlo = (size_t)l * T_ETYPES * D_H * D_H;
        const size_t blo = (size_t)l * T_ETYPES * D_H;
        if (l < L_LAYERS - 1) {
            tail_gemm<1><<<dim3(4, MB), blk, 0, stream>>>(
                h, neigh_b, wself_f + wlo, wneigh_f + wlo, bconv + blo, Rbuf);
            ln_sum_kernel<0><<<lngrid, blk, 0, stream>>>(
                Rbuf, gamma + blo, beta + blo, hn);
        } else {
            tail_gemm<0><<<dim3(4, MB), blk, 0, stream>>>(
                h, neigh_b, wself_f + wlo, wneigh_f + wlo, bconv + blo, Rbuf);
            ln_sum_kernel<1><<<lngrid, blk, 0, stream>>>(
                Rbuf, gamma + blo, beta + blo, d_out);
        }
        unsigned short* tmp = h; h = hn; hn = tmp;
    }
}

// Round 4
// 410.156 us; speedup vs baseline: 1.2735x; 1.1196x over previous
//
#include <hip/hip_runtime.h>

// Problem constants (from reference)
#define N_NODES 20000
#define F_IN    512
#define D_H     256
#define E_EDGES 200000
#define L_LAYERS 3
#define T_ETYPES 2

typedef __attribute__((ext_vector_type(8))) short bf16x8;
typedef __attribute__((ext_vector_type(4))) float f32x4;

__device__ __forceinline__ unsigned short f2b(float f) {
    unsigned int u = __float_as_uint(f);
    u = (u + 0x7FFFu + ((u >> 16) & 1u)) >> 16;   // round-nearest-even
    return (unsigned short)u;
}
__device__ __forceinline__ unsigned int pack2(float a, float b) {
    return (unsigned int)f2b(a) | ((unsigned int)f2b(b) << 16);
}

// async global->LDS, 16B per lane; LDS dest = wave-uniform base + lane*16,
// global source is per-lane (this is how we deposit fragment-slab order).
__device__ __forceinline__ void gload16(const unsigned short* g, unsigned short* l)
{
    __builtin_amdgcn_global_load_lds(
        (const __attribute__((address_space(1))) void*)g,
        (__attribute__((address_space(3))) void*)l, 16, 0, 0);
}

// ---------------- prep: weights -> bf16 fragment-slab order (gather) + x -> bf16 ----
// Fragment-slab layout for W[NO,K]: slab (n>>7, k>>5) is a contiguous 4096-elem (8KB)
// block; inside, elem (n_local,kk) at ((n_local>>4)&7)<<9 | ((kk>>3)&3)<<7
// | (n_local&15)<<3 | (kk&7). Gather form: each thread produces 8 consecutive dst
// elems (one 16B fragment run, fixed n, kk0..kk0+7) from 8 contiguous source fp32.
// Coalesced writes, 32B-chunk reads.
__device__ __forceinline__ void shufg8(const float* __restrict__ s,
                                       unsigned short* __restrict__ d,
                                       int NO, int K, int o8)
{
    const int matsz8 = (NO * K) >> 3;
    const int mat = o8 / matsz8;
    const int rem = o8 - mat * matsz8;
    const int dst = rem << 3;                  // dst elem index within mat
    const int slab = dst >> 12;
    const int w = dst & 4095;
    const int spr = K >> 5;                    // slabs per 128-row band
    const int slab_n = slab / spr, slab_k = slab - slab_n * spr;
    const int nl = (((w >> 9) & 7) << 4) + ((w >> 3) & 15);
    const int kk = ((w >> 7) & 3) << 3;
    const size_t soff = (size_t)mat * NO * K + (size_t)(slab_n * 128 + nl) * K
                      + slab_k * 32 + kk;
    const float4 a = *(const float4*)(s + soff);
    const float4 b = *(const float4*)(s + soff + 4);
    uint4 u;
    u.x = pack2(a.x, a.y); u.y = pack2(a.z, a.w);
    u.z = pack2(b.x, b.y); u.w = pack2(b.z, b.w);
    *(uint4*)(d + (size_t)mat * NO * K + dst) = u;
}

__global__ __launch_bounds__(256) void prep_kernel(
    const float* __restrict__ x,  unsigned short* __restrict__ xb, int nx8,
    const float* __restrict__ s0, unsigned short* __restrict__ d0, int NO0, int K0, int n08,
    const float* __restrict__ s1, unsigned short* __restrict__ d1, int NO1, int K1, int n18,
    const float* __restrict__ s2, unsigned short* __restrict__ d2, int NO2, int K2, int n28,
    const float* __restrict__ s3, unsigned short* __restrict__ d3, int NO3, int K3, int n38)
{
    int i = blockIdx.x * 256 + threadIdx.x;
    if (i < nx8) {
        const float4 a = ((const float4*)x)[i * 2];
        const float4 b = ((const float4*)x)[i * 2 + 1];
        uint4 u;
        u.x = pack2(a.x, a.y); u.y = pack2(a.z, a.w);
        u.z = pack2(b.x, b.y); u.w = pack2(b.z, b.w);
        ((uint4*)xb)[i] = u;
        return;
    }
    i -= nx8;
    if (i < n08) { shufg8(s0, d0, NO0, K0, i); return; }
    if ((i -= n08) < n18) { shufg8(s1, d1, NO1, K1, i); return; }
    if ((i -= n18) < n28) { shufg8(s2, d2, NO2, K2, i); return; }
    if ((i -= n28) < n38) { shufg8(s3, d3, NO3, K3, i); return; }
}

// ---------------- GEMM: triple-buffered LDS, counted-vmcnt pipeline ----------------
// C[M, bn:bn+128] = act(A @ W^T + bias). Block 128x128, 4 waves 2x2, wave 64x64.
// Stage runs 2 K-steps ahead; per-iteration s_waitcnt vmcnt(4) (one stage of 4
// loads/wave still in flight) + ONE raw s_barrier. vmcnt(0) only at the last step.
// Bias preloaded BEFORE the prologue so no stray VMEM corrupts the counted waits.
template <int NSTEPS>
__global__ __launch_bounds__(256) void gemm_lds(
    const unsigned short* __restrict__ A,   // [M, K] bf16, K = NSTEPS*32
    const unsigned short* __restrict__ Wf,  // fragment-slab weights, col-slab = blockIdx.x
    const float* __restrict__ bias, unsigned short* __restrict__ Cout,
    int M, int ldc, int relu)
{
    __shared__ __align__(16) unsigned short As[3][4096];  // 8KB per buf
    __shared__ __align__(16) unsigned short Bs[3][4096];
    const int K = NSTEPS * 32;
    const int tid = threadIdx.x, lane = tid & 63, w = tid >> 6;
    const int wm = w >> 1, wn = w & 1;
    const int bm = blockIdx.y * 128, bn = blockIdx.x * 128;
    const unsigned short* slab0 = Wf + (((size_t)blockIdx.x * NSTEPS) << 12);

    // A staging source precompute: chunk c = q*256+tid carries subtile mi=c>>6,
    // row r=(c&63)&15, k-quarter kq=(c&63)>>4 -> per-lane global offset (shorts).
    size_t aoff[2];
#pragma unroll
    for (int q = 0; q < 2; ++q) {
        const int c = q * 256 + tid;
        const int mi = c >> 6, ww = c & 63, r = ww & 15, kq = ww >> 4;
        const int rg = min(bm + mi * 16 + r, M - 1);
        aoff[q] = (size_t)rg * K + kq * 8;
    }

    // preload bias (issued before any staging -> drained by the first counted wait)
    const int cbase = bn + wn * 64 + (lane & 15);
    float bj[4];
#pragma unroll
    for (int j = 0; j < 4; ++j) bj[j] = bias[cbase + j * 16];
    asm volatile("" ::: "memory");

    f32x4 acc[4][4] = {};

#define GL_STAGE(S, BUF) do { \
    _Pragma("unroll") \
    for (int q_ = 0; q_ < 2; ++q_) { \
        gload16(A + aoff[q_] + (S) * 32, &As[BUF][(q_ * 256 + w * 64) * 8]); \
        gload16(slab0 + (((size_t)(S)) << 12) + (size_t)(q_ * 256 + tid) * 8, \
                &Bs[BUF][(q_ * 256 + w * 64) * 8]); \
    } \
} while (0)

    GL_STAGE(0, 0);
    GL_STAGE(1, 1);
#pragma unroll
    for (int s = 0; s < NSTEPS; ++s) {
        if (s + 1 < NSTEPS) asm volatile("s_waitcnt vmcnt(4)" ::: "memory");
        else                asm volatile("s_waitcnt vmcnt(0)" ::: "memory");
        __builtin_amdgcn_s_barrier();
        asm volatile("" ::: "memory");
        if (s + 2 < NSTEPS) GL_STAGE(s + 2, (s + 2) % 3);
        const int buf = s % 3;
        bf16x8 a[4], b[4];
#pragma unroll
        for (int mi = 0; mi < 4; ++mi)
            a[mi] = *(const bf16x8*)((const char*)As[buf] + ((wm * 4 + mi) << 10) + lane * 16);
#pragma unroll
        for (int j = 0; j < 4; ++j)
            b[j] = *(const bf16x8*)((const char*)Bs[buf] + ((wn * 4 + j) << 10) + lane * 16);
#pragma unroll
        for (int mi = 0; mi < 4; ++mi)
#pragma unroll
            for (int j = 0; j < 4; ++j)
                acc[mi][j] = __builtin_amdgcn_mfma_f32_16x16x32_bf16(a[mi], b[j], acc[mi][j], 0, 0, 0);
    }
#undef GL_STAGE

    // C/D layout: col = lane&15, row = (lane>>4)*4 + reg
    const int rb = bm + wm * 64 + ((lane >> 4) << 2);
#pragma unroll
    for (int j = 0; j < 4; ++j) {
#pragma unroll
        for (int mi = 0; mi < 4; ++mi)
#pragma unroll
            for (int r = 0; r < 4; ++r) {
                const int row = rb + mi * 16 + r;
                if (row < M) {
                    float v = acc[mi][j][r] + bj[j];
                    if (relu) v = fmaxf(v, 0.f);
                    Cout[(size_t)row * ldc + cbase + j * 16] = f2b(v);
                }
            }
    }
}

// ---------------- tail GEMM: R[N,512] = relu?(h@Ws[e]^T + neigh_e@Wn[e]^T + b) ------
// Same counted-vmcnt pipeline; K=512 streamed from two A sources
// (steps 0..7: h, steps 8..15: neigh slice for etype e = col-slab>>1). fp32 output.
template <int RELU>
__global__ __launch_bounds__(256) void tail_gemm(
    const unsigned short* __restrict__ h,      // [N,256] bf16
    const unsigned short* __restrict__ neigh,  // [N,512] bf16 (both etypes)
    const unsigned short* __restrict__ Ws,     // wself_f layer base (t0; t1 at +65536)
    const unsigned short* __restrict__ Wn,     // wneigh_f layer base
    const float* __restrict__ bias,            // [512] layer base
    float* __restrict__ R)                     // [N,512] fp32
{
    __shared__ __align__(16) unsigned short As[3][4096];
    __shared__ __align__(16) unsigned short Bs[3][4096];
    const int tid = threadIdx.x, lane = tid & 63, w = tid >> 6;
    const int wm = w >> 1, wn = w & 1;
    const int bm = blockIdx.y * 128;
    const int cs = blockIdx.x;                 // col-slab 0..3
    const int e  = cs >> 1;
    const unsigned short* Bself  = Ws + (size_t)e * 65536 + (cs & 1) * 32768;
    const unsigned short* Bneigh = Wn + (size_t)e * 65536 + (cs & 1) * 32768;

    size_t aoffH[2], aoffN[2];
#pragma unroll
    for (int q = 0; q < 2; ++q) {
        const int c = q * 256 + tid;
        const int mi = c >> 6, ww = c & 63, r = ww & 15, kq = ww >> 4;
        const int rg = min(bm + mi * 16 + r, N_NODES - 1);
        aoffH[q] = (size_t)rg * 256 + kq * 8;
        aoffN[q] = (size_t)rg * 512 + e * 256 + kq * 8;
    }

    const int cbase = cs * 128 + wn * 64 + (lane & 15);
    float bj[4];
#pragma unroll
    for (int j = 0; j < 4; ++j) bj[j] = bias[cbase + j * 16];
    asm volatile("" ::: "memory");

    f32x4 acc[4][4] = {};

#define TG_STAGE(S, BUF) do { \
    _Pragma("unroll") \
    for (int q_ = 0; q_ < 2; ++q_) { \
        const unsigned short* as_ = ((S) < 8) ? (h + aoffH[q_] + (S) * 32) \
                                              : (neigh + aoffN[q_] + ((S) - 8) * 32); \
        gload16(as_, &As[BUF][(q_ * 256 + w * 64) * 8]); \
        const unsigned short* bs_ = (((S) < 8) ? (Bself + (S) * 4096) \
                                               : (Bneigh + ((S) - 8) * 4096)) \
                                    + (size_t)(q_ * 256 + tid) * 8; \
        gload16(bs_, &Bs[BUF][(q_ * 256 + w * 64) * 8]); \
    } \
} while (0)

    TG_STAGE(0, 0);
    TG_STAGE(1, 1);
#pragma unroll
    for (int s = 0; s < 16; ++s) {
        if (s + 1 < 16) asm volatile("s_waitcnt vmcnt(4)" ::: "memory");
        else            asm volatile("s_waitcnt vmcnt(0)" ::: "memory");
        __builtin_amdgcn_s_barrier();
        asm volatile("" ::: "memory");
        if (s + 2 < 16) TG_STAGE(s + 2, (s + 2) % 3);
        const int buf = s % 3;
        bf16x8 a[4], b[4];
#pragma unroll
        for (int mi = 0; mi < 4; ++mi)
            a[mi] = *(const bf16x8*)((const char*)As[buf] + ((wm * 4 + mi) << 10) + lane * 16);
#pragma unroll
        for (int j = 0; j < 4; ++j)
            b[j] = *(const bf16x8*)((const char*)Bs[buf] + ((wn * 4 + j) << 10) + lane * 16);
#pragma unroll
        for (int mi = 0; mi < 4; ++mi)
#pragma unroll
            for (int j = 0; j < 4; ++j)
                acc[mi][j] = __builtin_amdgcn_mfma_f32_16x16x32_bf16(a[mi], b[j], acc[mi][j], 0, 0, 0);
    }
#undef TG_STAGE

    const int rb = bm + wm * 64 + ((lane >> 4) << 2);
#pragma unroll
    for (int j = 0; j < 4; ++j) {
#pragma unroll
        for (int mi = 0; mi < 4; ++mi)
#pragma unroll
            for (int r = 0; r < 4; ++r) {
                const int row = rb + mi * 16 + r;
                if (row < N_NODES) {
                    float v = acc[mi][j][r] + bj[j];
                    if (RELU) v = fmaxf(v, 0.f);
                    R[(size_t)row * 512 + cbase + j * 16] = v;
                }
            }
    }
}

// ---------------- LN + etype-sum: out[r] = LN0(R[r,0:256]) + LN1(R[r,256:512]) ------
// One wave per row; memory-bound (R is L3-resident).
template <int LAST>
__global__ __launch_bounds__(256) void ln_sum_kernel(
    const float* __restrict__ R,               // [N,512] fp32 (relu already applied)
    const float* __restrict__ gamma,           // [512] layer base
    const float* __restrict__ beta,
    void* __restrict__ outp)                   // bf16 [N,256] or fp32 [N,256]
{
    const int row  = blockIdx.x * 4 + (threadIdx.x >> 6);
    const int lane = threadIdx.x & 63;
    const float4 v0 = ((const float4*)R)[(size_t)row * 128 + lane];
    const float4 v1 = ((const float4*)R)[(size_t)row * 128 + 64 + lane];
    float s0 = v0.x + v0.y + v0.z + v0.w;
    float q0 = v0.x * v0.x + v0.y * v0.y + v0.z * v0.z + v0.w * v0.w;
    float s1 = v1.x + v1.y + v1.z + v1.w;
    float q1 = v1.x * v1.x + v1.y * v1.y + v1.z * v1.z + v1.w * v1.w;
#pragma unroll
    for (int o = 1; o < 64; o <<= 1) {
        s0 += __shfl_xor(s0, o); q0 += __shfl_xor(q0, o);
        s1 += __shfl_xor(s1, o); q1 += __shfl_xor(q1, o);
    }
    const float m0 = s0 * (1.f / 256.f), m1 = s1 * (1.f / 256.f);
    const float i0 = rsqrtf(q0 * (1.f / 256.f) - m0 * m0 + 1e-5f);
    const float i1 = rsqrtf(q1 * (1.f / 256.f) - m1 * m1 + 1e-5f);
    const float4 g0 = ((const float4*)gamma)[lane];
    const float4 b0 = ((const float4*)beta)[lane];
    const float4 g1 = ((const float4*)(gamma + 256))[lane];
    const float4 b1 = ((const float4*)(beta + 256))[lane];
    const float o0 = (v0.x - m0) * i0 * g0.x + b0.x + (v1.x - m1) * i1 * g1.x + b1.x;
    const float o1 = (v0.y - m0) * i0 * g0.y + b0.y + (v1.y - m1) * i1 * g1.y + b1.y;
    const float o2 = (v0.z - m0) * i0 * g0.z + b0.z + (v1.z - m1) * i1 * g1.z + b1.z;
    const float o3 = (v0.w - m0) * i0 * g0.w + b0.w + (v1.w - m1) * i1 * g1.w + b1.w;
    if (LAST) {
        ((float4*)outp)[(size_t)row * 64 + lane] = make_float4(o0, o1, o2, o3);
    } else {
        ushort4 u;
        u.x = f2b(o0); u.y = f2b(o1); u.z = f2b(o2); u.w = f2b(o3);
        ((ushort4*)outp)[(size_t)row * 64 + lane] = u;
    }
}

// ---------------- CSR build (both etypes batched; once per launch) ----------------
__global__ __launch_bounds__(256) void count_deg_kernel(
    const int* __restrict__ dst, int* __restrict__ cnt, int E2)
{
    int e = blockIdx.x * 256 + threadIdx.x;
    if (e < E2) {
        const int base = (e >= E_EDGES) ? N_NODES : 0;
        atomicAdd(&cnt[base + dst[e]], 1);
    }
}

__global__ __launch_bounds__(256) void scanA_kernel(
    const int* __restrict__ cnt, int* __restrict__ incl, int* __restrict__ bsum, int n)
{
    __shared__ int tmp[256];
    const int tid = threadIdx.x;
    const int i = blockIdx.x * 256 + tid;
    const int v = (i < n) ? cnt[i] : 0;
    tmp[tid] = v;
    __syncthreads();
#pragma unroll
    for (int o = 1; o < 256; o <<= 1) {
        const int t = (tid >= o) ? tmp[tid - o] : 0;
        __syncthreads();
        tmp[tid] += t;
        __syncthreads();
    }
    if (i < n) incl[i] = tmp[tid];
    if (tid == 255) bsum[blockIdx.x] = tmp[255];
}

__global__ __launch_bounds__(256) void scanB_kernel(int* __restrict__ bsum, int nb)
{
    __shared__ int tmp[256];
    const int tid = threadIdx.x;
    const int v = (tid < nb) ? bsum[tid] : 0;
    tmp[tid] = v;
    __syncthreads();
#pragma unroll
    for (int o = 1; o < 256; o <<= 1) {
        const int t = (tid >= o) ? tmp[tid - o] : 0;
        __syncthreads();
        tmp[tid] += t;
        __syncthreads();
    }
    if (tid < nb) bsum[tid] = tmp[tid] - v;  // exclusive
}

__global__ __launch_bounds__(256) void scanC_kernel(
    const int* __restrict__ cnt, const int* __restrict__ incl,
    const int* __restrict__ bsum, int* __restrict__ off, int* __restrict__ cursor, int n)
{
    const int i = blockIdx.x * 256 + threadIdx.x;
    if (i < n) {
        const int e = incl[i] + bsum[blockIdx.x];
        off[i + 1] = e;
        cursor[i] = e - cnt[i];
    }
    if (i == 0) off[0] = 0;
}

__global__ __launch_bounds__(256) void fill_csr_kernel(
    const int* __restrict__ src, const int* __restrict__ dst,
    int* __restrict__ cursor, int* __restrict__ esrc, int E2)
{
    int e = blockIdx.x * 256 + threadIdx.x;
    if (e < E2) {
        const int base = (e >= E_EDGES) ? N_NODES : 0;
        const int pos = atomicAdd(&cursor[base + dst[e]], 1);
        esrc[pos] = src[e];
    }
}

// ---------------- segment max (bf16, both etypes): one wave per (node,t) ----------------
__device__ __forceinline__ ushort4 umax4(ushort4 a, ushort4 b)
{
    a.x = a.x > b.x ? a.x : b.x;
    a.y = a.y > b.y ? a.y : b.y;
    a.z = a.z > b.z ? a.z : b.z;
    a.w = a.w > b.w ? a.w : b.w;
    return a;
}

__global__ __launch_bounds__(256) void seg_max_kernel(
    const unsigned short* __restrict__ hp, const int* __restrict__ off,
    const int* __restrict__ esrc, unsigned short* __restrict__ neigh)
{
    const int g = blockIdx.x * 4 + (threadIdx.x >> 6);
    if (g >= 2 * N_NODES) return;
    const int t = (g >= N_NODES) ? 1 : 0;
    const int node = g - t * N_NODES;
    const int lane = threadIdx.x & 63;
    const int co = t * D_H + lane * 4;
    const int e0 = off[g], e1 = off[g + 1];
    ushort4 acc = make_ushort4(0, 0, 0, 0);
    int e = e0;
    for (; e + 4 <= e1; e += 4) {
        const int s0 = esrc[e + 0], s1 = esrc[e + 1];
        const int s2 = esrc[e + 2], s3 = esrc[e + 3];
        const ushort4 v0 = *(const ushort4*)(hp + (size_t)s0 * 512 + co);
        const ushort4 v1 = *(const ushort4*)(hp + (size_t)s1 * 512 + co);
        const ushort4 v2 = *(const ushort4*)(hp + (size_t)s2 * 512 + co);
        const ushort4 v3 = *(const ushort4*)(hp + (size_t)s3 * 512 + co);
        acc = umax4(umax4(umax4(acc, v0), umax4(v1, v2)), v3);
    }
    for (; e < e1; ++e)
        acc = umax4(acc, *(const ushort4*)(hp + (size_t)esrc[e] * 512 + co));
    *(ushort4*)(neigh + (size_t)node * 512 + co) = acc;
}

extern "C" void kernel_launch(void* const* d_in, const int* in_sizes, int n_in,
                              void* d_out, int out_size, void* d_ws, size_t ws_size,
                              hipStream_t stream)
{
    const float* x      = (const float*)d_in[0];
    const int*   src    = (const int*)d_in[1];
    const int*   dst    = (const int*)d_in[2];
    const float* Wlin   = (const float*)d_in[3];
    const float* blin   = (const float*)d_in[4];
    const float* Wpool  = (const float*)d_in[5];
    const float* bpool  = (const float*)d_in[6];
    const float* Wself  = (const float*)d_in[7];
    const float* Wneigh = (const float*)d_in[8];
    const float* bconv  = (const float*)d_in[9];
    const float* gamma  = (const float*)d_in[10];
    const float* beta   = (const float*)d_in[11];

    const size_t NB = (size_t)N_NODES * D_H;  // 5.12M
    char* p = (char*)d_ws;
    unsigned short* hp_b    = (unsigned short*)p; p += NB * 2 * T_ETYPES;  // [N,512]
    unsigned short* neigh_b = (unsigned short*)p; p += NB * 2 * T_ETYPES;  // [N,512]
    unsigned short* h_a     = (unsigned short*)p; p += NB * 2;
    unsigned short* h_b     = (unsigned short*)p; p += NB * 2;
    unsigned short* xb      = (unsigned short*)p; p += (size_t)N_NODES * F_IN * 2;  // 20.48MB
    float*          Rbuf    = (float*)p;          p += (size_t)N_NODES * 512 * 4;   // 40.96MB
    unsigned short* wlin_f  = (unsigned short*)p; p += (size_t)D_H * F_IN * 2;
    const size_t WSZ = (size_t)L_LAYERS * T_ETYPES * D_H * D_H;  // 393216
    unsigned short* wpool_f = (unsigned short*)p; p += WSZ * 2;
    unsigned short* wself_f = (unsigned short*)p; p += WSZ * 2;
    unsigned short* wneigh_f= (unsigned short*)p; p += WSZ * 2;
    int* ip = (int*)p;
    const int NT = T_ETYPES * N_NODES;  // 40000
    int* cnt    = ip; ip += NT;
    int* incl   = ip; ip += NT;
    int* off    = ip; ip += NT + 1;
    int* cursor = ip; ip += NT;
    int* esrc   = ip; ip += T_ETYPES * E_EDGES;
    int* bsum   = ip; ip += 256;

    const dim3 blk(256);
    const int E2 = T_ETYPES * E_EDGES;
    const dim3 e2grid((E2 + 255) / 256);
    const int nScanBlk = (NT + 255) / 256;  // 157

    // ---- prep: x->bf16 + all weights -> fragment-slab bf16, one dispatch ----
    {
        const int nx8  = N_NODES * F_IN / 8;        // 1,280,000
        const int nl8  = D_H * F_IN / 8;            // 16384
        const int nw8  = (int)(WSZ / 8);            // 49152
        const int tot  = nx8 + nl8 + 3 * nw8;
        prep_kernel<<<dim3((tot + 255) / 256), blk, 0, stream>>>(
            x, xb, nx8,
            Wlin, wlin_f, D_H, F_IN, nl8,
            Wpool, wpool_f, T_ETYPES * D_H, D_H, nw8,   // per layer: [512,256]
            Wself, wself_f, D_H, D_H, nw8,              // per (l,t): [256,256]
            Wneigh, wneigh_f, D_H, D_H, nw8);
    }

    // ---- CSR build, both etypes batched ----
    hipMemsetAsync(cnt, 0, (size_t)NT * sizeof(int), stream);
    count_deg_kernel<<<e2grid, blk, 0, stream>>>(dst, cnt, E2);
    scanA_kernel<<<dim3(nScanBlk), blk, 0, stream>>>(cnt, incl, bsum, NT);
    scanB_kernel<<<dim3(1), blk, 0, stream>>>(bsum, nScanBlk);
    scanC_kernel<<<dim3(nScanBlk), blk, 0, stream>>>(cnt, incl, bsum, off, cursor, NT);
    fill_csr_kernel<<<e2grid, blk, 0, stream>>>(src, dst, cursor, esrc, E2);

    const int MB = (N_NODES + 127) / 128;  // 157

    // ---- h0 = bf16(xb @ Wlin^T + blin), K=512 ----
    gemm_lds<16><<<dim3(2, MB), blk, 0, stream>>>(
        xb, wlin_f, blin, h_a, N_NODES, D_H, 0);

    unsigned short* h = h_a;
    unsigned short* hn = h_b;
    const dim3 sgrid((2 * N_NODES + 3) / 4);
    const dim3 lngrid(N_NODES / 4);             // 5000, exact
    for (int l = 0; l < L_LAYERS; ++l) {
        // hp[:, t*256:] = bf16(relu(h @ Wpool[l,t]^T + bpool[l,t])), both t in one dispatch
        gemm_lds<8><<<dim3(4, MB), blk, 0, stream>>>(
            h, wpool_f + (size_t)l * T_ETYPES * D_H * D_H,
            bpool + (size_t)l * T_ETYPES * D_H, hp_b, N_NODES, T_ETYPES * D_H, 1);
        // neigh = segment_max per (node, t)
        seg_max_kernel<<<sgrid, blk, 0, stream>>>(hp_b, off, esrc, neigh_b);
        // tail GEMM -> R fp32 (relu'd, bias'd), then LN+sum
        const size_t wlo = (size_t)l * T_ETYPES * D_H * D_H;
        const size_t blo = (size_t)l * T_ETYPES * D_H;
        if (l < L_LAYERS - 1) {
            tail_gemm<1><<<dim3(4, MB), blk, 0, stream>>>(
                h, neigh_b, wself_f + wlo, wneigh_f + wlo, bconv + blo, Rbuf);
            ln_sum_kernel<0><<<lngrid, blk, 0, stream>>>(
                Rbuf, gamma + blo, beta + blo, hn);
        } else {
            tail_gemm<0><<<dim3(4, MB), blk, 0, stream>>>(
                h, neigh_b, wself_f + wlo, wneigh_f + wlo, bconv + blo, Rbuf);
            ln_sum_kernel<1><<<lngrid, blk, 0, stream>>>(
                Rbuf, gamma + blo, beta + blo, d_out);
        }
        unsigned short* tmp = h; h = hn; hn = tmp;
    }
}

// Round 5
// 390.564 us; speedup vs baseline: 1.3373x; 1.0502x over previous
//
#include <hip/hip_runtime.h>

// Problem constants (from reference)
#define N_NODES 20000
#define F_IN    512
#define D_H     256
#define E_EDGES 200000
#define L_LAYERS 3
#define T_ETYPES 2

typedef __attribute__((ext_vector_type(8))) short bf16x8;
typedef __attribute__((ext_vector_type(4))) float f32x4;

__device__ __forceinline__ unsigned short f2b(float f) {
    unsigned int u = __float_as_uint(f);
    u = (u + 0x7FFFu + ((u >> 16) & 1u)) >> 16;   // round-nearest-even
    return (unsigned short)u;
}
__device__ __forceinline__ unsigned int pack2(float a, float b) {
    return (unsigned int)f2b(a) | ((unsigned int)f2b(b) << 16);
}

// async global->LDS, 16B per lane; LDS dest = wave-uniform base + lane*16,
// global source is per-lane (this is how we deposit fragment-slab order).
__device__ __forceinline__ void gload16(const unsigned short* g, unsigned short* l)
{
    __builtin_amdgcn_global_load_lds(
        (const __attribute__((address_space(1))) void*)g,
        (__attribute__((address_space(3))) void*)l, 16, 0, 0);
}

// ---------------- prep: weights -> bf16 fragment-slab order (gather) + x -> bf16 ----
// Fragment-slab layout for W[NO,K]: slab (n>>7, k>>5) is a contiguous 4096-elem (8KB)
// block; inside, elem (n_local,kk) at ((n_local>>4)&7)<<9 | ((kk>>3)&3)<<7
// | (n_local&15)<<3 | (kk&7). Gather form: each thread produces 8 consecutive dst
// elems (one 16B fragment run) from 8 contiguous source fp32.
__device__ __forceinline__ void shufg8(const float* __restrict__ s,
                                       unsigned short* __restrict__ d,
                                       int NO, int K, int o8)
{
    const int matsz8 = (NO * K) >> 3;
    const int mat = o8 / matsz8;
    const int rem = o8 - mat * matsz8;
    const int dst = rem << 3;                  // dst elem index within mat
    const int slab = dst >> 12;
    const int w = dst & 4095;
    const int spr = K >> 5;                    // slabs per 128-row band
    const int slab_n = slab / spr, slab_k = slab - slab_n * spr;
    const int nl = (((w >> 9) & 7) << 4) + ((w >> 3) & 15);
    const int kk = ((w >> 7) & 3) << 3;
    const size_t soff = (size_t)mat * NO * K + (size_t)(slab_n * 128 + nl) * K
                      + slab_k * 32 + kk;
    const float4 a = *(const float4*)(s + soff);
    const float4 b = *(const float4*)(s + soff + 4);
    uint4 u;
    u.x = pack2(a.x, a.y); u.y = pack2(a.z, a.w);
    u.z = pack2(b.x, b.y); u.w = pack2(b.z, b.w);
    *(uint4*)(d + (size_t)mat * NO * K + dst) = u;
}

__global__ __launch_bounds__(256) void prep_kernel(
    const float* __restrict__ x,  unsigned short* __restrict__ xb, int nx8,
    const float* __restrict__ s0, unsigned short* __restrict__ d0, int NO0, int K0, int n08,
    const float* __restrict__ s1, unsigned short* __restrict__ d1, int NO1, int K1, int n18,
    const float* __restrict__ s2, unsigned short* __restrict__ d2, int NO2, int K2, int n28,
    const float* __restrict__ s3, unsigned short* __restrict__ d3, int NO3, int K3, int n38)
{
    int i = blockIdx.x * 256 + threadIdx.x;
    if (i < nx8) {
        const float4 a = ((const float4*)x)[i * 2];
        const float4 b = ((const float4*)x)[i * 2 + 1];
        uint4 u;
        u.x = pack2(a.x, a.y); u.y = pack2(a.z, a.w);
        u.z = pack2(b.x, b.y); u.w = pack2(b.z, b.w);
        ((uint4*)xb)[i] = u;
        return;
    }
    i -= nx8;
    if (i < n08) { shufg8(s0, d0, NO0, K0, i); return; }
    if ((i -= n08) < n18) { shufg8(s1, d1, NO1, K1, i); return; }
    if ((i -= n18) < n28) { shufg8(s2, d2, NO2, K2, i); return; }
    if ((i -= n28) < n38) { shufg8(s3, d3, NO3, K3, i); return; }
}

// ---------------- GEMM: 512-thr, triple-buffered LDS, counted-vmcnt, XCD swizzle ---
// C[M, cs*128 : +128] = act(A @ W^T + bias). Block 128x128, 8 waves 2x4, wave 64x32.
// Grid is 1-D swizzled: id = g*(8*CS) + cs*8 + bm8  =>  XCD(id%8) = bm8, so all CS
// col-slabs of one row-tile share an XCD and its L2 caches the A rows.
// Pipeline: stage 2 K-steps ahead (2 loads/wave/stage); steady wait vmcnt(2),
// vmcnt(0) only at the last step; one raw s_barrier per step.
template <int NSTEPS, int CS>
__global__ __launch_bounds__(512) void gemm_lds(
    const unsigned short* __restrict__ A,   // [M, K] bf16, K = NSTEPS*32
    const unsigned short* __restrict__ Wf,  // fragment-slab weights, col-slab = cs
    const float* __restrict__ bias, unsigned short* __restrict__ Cout,
    int M, int ldc, int relu)
{
    __shared__ __align__(16) unsigned short As[3][4096];  // 8KB per buf
    __shared__ __align__(16) unsigned short Bs[3][4096];
    const int K = NSTEPS * 32;
    const int tid = threadIdx.x, lane = tid & 63;
    const int w = tid >> 6, wm = w >> 2, wn = w & 3;
    // swizzle decode (padded row-tile groups of 8; early-exit on pad)
    const int id = blockIdx.x;
    const int g = id / (8 * CS), rem = id - g * (8 * CS);
    const int cs = rem >> 3, bmi = (g << 3) | (rem & 7);
    const int MB = (M + 127) >> 7;
    if (bmi >= MB) return;
    const int bm = bmi * 128;
    const unsigned short* slab0 = Wf + (((size_t)cs * NSTEPS) << 12);

    // A staging source: chunk tid -> subtile mi=tid>>6, row r=tid&15, kq=(tid>>4)&3
    const int rg = min(bm + ((tid >> 6) << 4) + (tid & 15), M - 1);
    const size_t aoff = (size_t)rg * K + ((tid >> 4) & 3) * 8;
    const unsigned short* bsrc = slab0 + (size_t)tid * 8;

    // preload bias (issued before staging; retired by the first counted wait)
    const int cbase = cs * 128 + wn * 32 + (lane & 15);
    float bj[2];
#pragma unroll
    for (int j = 0; j < 2; ++j) bj[j] = bias[cbase + j * 16];
    asm volatile("" ::: "memory");

    f32x4 acc[4][2] = {};

#define GL_STAGE(S, BUF) do { \
    gload16(A + aoff + (S) * 32, &As[BUF][(size_t)tid * 8]); \
    gload16(bsrc + (((size_t)(S)) << 12), &Bs[BUF][(size_t)tid * 8]); \
} while (0)

    GL_STAGE(0, 0);
    GL_STAGE(1, 1);
#pragma unroll
    for (int s = 0; s < NSTEPS; ++s) {
        if (s + 1 < NSTEPS) asm volatile("s_waitcnt vmcnt(2)" ::: "memory");
        else                asm volatile("s_waitcnt vmcnt(0)" ::: "memory");
        __builtin_amdgcn_s_barrier();
        asm volatile("" ::: "memory");
        if (s + 2 < NSTEPS) GL_STAGE(s + 2, (s + 2) % 3);
        const int buf = s % 3;
        bf16x8 a[4], b[2];
#pragma unroll
        for (int mi = 0; mi < 4; ++mi)
            a[mi] = *(const bf16x8*)((const char*)As[buf] + ((wm * 4 + mi) << 10) + lane * 16);
#pragma unroll
        for (int j = 0; j < 2; ++j)
            b[j] = *(const bf16x8*)((const char*)Bs[buf] + ((wn * 2 + j) << 10) + lane * 16);
#pragma unroll
        for (int mi = 0; mi < 4; ++mi)
#pragma unroll
            for (int j = 0; j < 2; ++j)
                acc[mi][j] = __builtin_amdgcn_mfma_f32_16x16x32_bf16(a[mi], b[j], acc[mi][j], 0, 0, 0);
    }
#undef GL_STAGE

    // C/D layout: col = lane&15, row = (lane>>4)*4 + reg
    const int rb = bm + wm * 64 + ((lane >> 4) << 2);
#pragma unroll
    for (int j = 0; j < 2; ++j) {
#pragma unroll
        for (int mi = 0; mi < 4; ++mi)
#pragma unroll
            for (int r = 0; r < 4; ++r) {
                const int row = rb + mi * 16 + r;
                if (row < M) {
                    float v = acc[mi][j][r] + bj[j];
                    if (relu) v = fmaxf(v, 0.f);
                    Cout[(size_t)row * ldc + cbase + j * 16] = f2b(v);
                }
            }
    }
}

// ---------------- tail GEMM: R[N,512] = relu?(h@Ws[e]^T + neigh_e@Wn[e]^T + b) ------
// Same 512-thr pipeline + swizzle; K=512 from two A sources (steps 0..7: h,
// steps 8..15: neigh slice for etype e = cs>>1). fp32 output.
template <int RELU>
__global__ __launch_bounds__(512) void tail_gemm(
    const unsigned short* __restrict__ h,      // [N,256] bf16
    const unsigned short* __restrict__ neigh,  // [N,512] bf16 (both etypes)
    const unsigned short* __restrict__ Ws,     // wself_f layer base (t0; t1 at +65536)
    const unsigned short* __restrict__ Wn,     // wneigh_f layer base
    const float* __restrict__ bias,            // [512] layer base
    float* __restrict__ R)                     // [N,512] fp32
{
    __shared__ __align__(16) unsigned short As[3][4096];
    __shared__ __align__(16) unsigned short Bs[3][4096];
    const int tid = threadIdx.x, lane = tid & 63;
    const int w = tid >> 6, wm = w >> 2, wn = w & 3;
    const int id = blockIdx.x;
    const int g = id >> 5, rem = id & 31;      // CS = 4
    const int cs = rem >> 3, bmi = (g << 3) | (rem & 7);
    const int MB = (N_NODES + 127) >> 7;       // 157
    if (bmi >= MB) return;
    const int bm = bmi * 128;
    const int e  = cs >> 1;
    const unsigned short* Bself  = Ws + (size_t)e * 65536 + (cs & 1) * 32768;
    const unsigned short* Bneigh = Wn + (size_t)e * 65536 + (cs & 1) * 32768;

    const int rg = min(bm + ((tid >> 6) << 4) + (tid & 15), N_NODES - 1);
    const size_t aoffH = (size_t)rg * 256 + ((tid >> 4) & 3) * 8;
    const size_t aoffN = (size_t)rg * 512 + e * 256 + ((tid >> 4) & 3) * 8;

    const int cbase = cs * 128 + wn * 32 + (lane & 15);
    float bj[2];
#pragma unroll
    for (int j = 0; j < 2; ++j) bj[j] = bias[cbase + j * 16];
    asm volatile("" ::: "memory");

    f32x4 acc[4][2] = {};

#define TG_STAGE(S, BUF) do { \
    const unsigned short* as_ = ((S) < 8) ? (h + aoffH + (S) * 32) \
                                          : (neigh + aoffN + ((S) - 8) * 32); \
    gload16(as_, &As[BUF][(size_t)tid * 8]); \
    const unsigned short* bs_ = (((S) < 8) ? (Bself + (S) * 4096) \
                                           : (Bneigh + ((S) - 8) * 4096)) \
                                + (size_t)tid * 8; \
    gload16(bs_, &Bs[BUF][(size_t)tid * 8]); \
} while (0)

    TG_STAGE(0, 0);
    TG_STAGE(1, 1);
#pragma unroll
    for (int s = 0; s < 16; ++s) {
        if (s + 1 < 16) asm volatile("s_waitcnt vmcnt(2)" ::: "memory");
        else            asm volatile("s_waitcnt vmcnt(0)" ::: "memory");
        __builtin_amdgcn_s_barrier();
        asm volatile("" ::: "memory");
        if (s + 2 < 16) TG_STAGE(s + 2, (s + 2) % 3);
        const int buf = s % 3;
        bf16x8 a[4], b[2];
#pragma unroll
        for (int mi = 0; mi < 4; ++mi)
            a[mi] = *(const bf16x8*)((const char*)As[buf] + ((wm * 4 + mi) << 10) + lane * 16);
#pragma unroll
        for (int j = 0; j < 2; ++j)
            b[j] = *(const bf16x8*)((const char*)Bs[buf] + ((wn * 2 + j) << 10) + lane * 16);
#pragma unroll
        for (int mi = 0; mi < 4; ++mi)
#pragma unroll
            for (int j = 0; j < 2; ++j)
                acc[mi][j] = __builtin_amdgcn_mfma_f32_16x16x32_bf16(a[mi], b[j], acc[mi][j], 0, 0, 0);
    }
#undef TG_STAGE

    const int rb = bm + wm * 64 + ((lane >> 4) << 2);
#pragma unroll
    for (int j = 0; j < 2; ++j) {
#pragma unroll
        for (int mi = 0; mi < 4; ++mi)
#pragma unroll
            for (int r = 0; r < 4; ++r) {
                const int row = rb + mi * 16 + r;
                if (row < N_NODES) {
                    float v = acc[mi][j][r] + bj[j];
                    if (RELU) v = fmaxf(v, 0.f);
                    R[(size_t)row * 512 + cbase + j * 16] = v;
                }
            }
    }
}

// ---------------- LN + etype-sum: out[r] = LN0(R[r,0:256]) + LN1(R[r,256:512]) ------
template <int LAST>
__global__ __launch_bounds__(256) void ln_sum_kernel(
    const float* __restrict__ R,               // [N,512] fp32 (relu already applied)
    const float* __restrict__ gamma,           // [512] layer base
    const float* __restrict__ beta,
    void* __restrict__ outp)                   // bf16 [N,256] or fp32 [N,256]
{
    const int row  = blockIdx.x * 4 + (threadIdx.x >> 6);
    const int lane = threadIdx.x & 63;
    const float4 v0 = ((const float4*)R)[(size_t)row * 128 + lane];
    const float4 v1 = ((const float4*)R)[(size_t)row * 128 + 64 + lane];
    float s0 = v0.x + v0.y + v0.z + v0.w;
    float q0 = v0.x * v0.x + v0.y * v0.y + v0.z * v0.z + v0.w * v0.w;
    float s1 = v1.x + v1.y + v1.z + v1.w;
    float q1 = v1.x * v1.x + v1.y * v1.y + v1.z * v1.z + v1.w * v1.w;
#pragma unroll
    for (int o = 1; o < 64; o <<= 1) {
        s0 += __shfl_xor(s0, o); q0 += __shfl_xor(q0, o);
        s1 += __shfl_xor(s1, o); q1 += __shfl_xor(q1, o);
    }
    const float m0 = s0 * (1.f / 256.f), m1 = s1 * (1.f / 256.f);
    const float i0 = rsqrtf(q0 * (1.f / 256.f) - m0 * m0 + 1e-5f);
    const float i1 = rsqrtf(q1 * (1.f / 256.f) - m1 * m1 + 1e-5f);
    const float4 g0 = ((const float4*)gamma)[lane];
    const float4 b0 = ((const float4*)beta)[lane];
    const float4 g1 = ((const float4*)(gamma + 256))[lane];
    const float4 b1 = ((const float4*)(beta + 256))[lane];
    const float o0 = (v0.x - m0) * i0 * g0.x + b0.x + (v1.x - m1) * i1 * g1.x + b1.x;
    const float o1 = (v0.y - m0) * i0 * g0.y + b0.y + (v1.y - m1) * i1 * g1.y + b1.y;
    const float o2 = (v0.z - m0) * i0 * g0.z + b0.z + (v1.z - m1) * i1 * g1.z + b1.z;
    const float o3 = (v0.w - m0) * i0 * g0.w + b0.w + (v1.w - m1) * i1 * g1.w + b1.w;
    if (LAST) {
        ((float4*)outp)[(size_t)row * 64 + lane] = make_float4(o0, o1, o2, o3);
    } else {
        ushort4 u;
        u.x = f2b(o0); u.y = f2b(o1); u.z = f2b(o2); u.w = f2b(o3);
        ((ushort4*)outp)[(size_t)row * 64 + lane] = u;
    }
}

// ---------------- CSR build (both etypes batched; once per launch) ----------------
__global__ __launch_bounds__(256) void count_deg_kernel(
    const int* __restrict__ dst, int* __restrict__ cnt, int E2)
{
    int e = blockIdx.x * 256 + threadIdx.x;
    if (e < E2) {
        const int base = (e >= E_EDGES) ? N_NODES : 0;
        atomicAdd(&cnt[base + dst[e]], 1);
    }
}

__global__ __launch_bounds__(256) void scanA_kernel(
    const int* __restrict__ cnt, int* __restrict__ incl, int* __restrict__ bsum, int n)
{
    __shared__ int tmp[256];
    const int tid = threadIdx.x;
    const int i = blockIdx.x * 256 + tid;
    const int v = (i < n) ? cnt[i] : 0;
    tmp[tid] = v;
    __syncthreads();
#pragma unroll
    for (int o = 1; o < 256; o <<= 1) {
        const int t = (tid >= o) ? tmp[tid - o] : 0;
        __syncthreads();
        tmp[tid] += t;
        __syncthreads();
    }
    if (i < n) incl[i] = tmp[tid];
    if (tid == 255) bsum[blockIdx.x] = tmp[255];
}

__global__ __launch_bounds__(256) void scanB_kernel(int* __restrict__ bsum, int nb)
{
    __shared__ int tmp[256];
    const int tid = threadIdx.x;
    const int v = (tid < nb) ? bsum[tid] : 0;
    tmp[tid] = v;
    __syncthreads();
#pragma unroll
    for (int o = 1; o < 256; o <<= 1) {
        const int t = (tid >= o) ? tmp[tid - o] : 0;
        __syncthreads();
        tmp[tid] += t;
        __syncthreads();
    }
    if (tid < nb) bsum[tid] = tmp[tid] - v;  // exclusive
}

__global__ __launch_bounds__(256) void scanC_kernel(
    const int* __restrict__ cnt, const int* __restrict__ incl,
    const int* __restrict__ bsum, int* __restrict__ off, int* __restrict__ cursor, int n)
{
    const int i = blockIdx.x * 256 + threadIdx.x;
    if (i < n) {
        const int e = incl[i] + bsum[blockIdx.x];
        off[i + 1] = e;
        cursor[i] = e - cnt[i];
    }
    if (i == 0) off[0] = 0;
}

__global__ __launch_bounds__(256) void fill_csr_kernel(
    const int* __restrict__ src, const int* __restrict__ dst,
    int* __restrict__ cursor, int* __restrict__ esrc, int E2)
{
    int e = blockIdx.x * 256 + threadIdx.x;
    if (e < E2) {
        const int base = (e >= E_EDGES) ? N_NODES : 0;
        const int pos = atomicAdd(&cursor[base + dst[e]], 1);
        esrc[pos] = src[e];
    }
}

// ---------------- segment max (bf16, both etypes): one wave per (node,t) ----------------
__device__ __forceinline__ ushort4 umax4(ushort4 a, ushort4 b)
{
    a.x = a.x > b.x ? a.x : b.x;
    a.y = a.y > b.y ? a.y : b.y;
    a.z = a.z > b.z ? a.z : b.z;
    a.w = a.w > b.w ? a.w : b.w;
    return a;
}

__global__ __launch_bounds__(256) void seg_max_kernel(
    const unsigned short* __restrict__ hp, const int* __restrict__ off,
    const int* __restrict__ esrc, unsigned short* __restrict__ neigh)
{
    const int g = blockIdx.x * 4 + (threadIdx.x >> 6);
    if (g >= 2 * N_NODES) return;
    const int t = (g >= N_NODES) ? 1 : 0;
    const int node = g - t * N_NODES;
    const int lane = threadIdx.x & 63;
    const int co = t * D_H + lane * 4;
    const int e0 = off[g], e1 = off[g + 1];
    ushort4 acc = make_ushort4(0, 0, 0, 0);
    int e = e0;
    for (; e + 4 <= e1; e += 4) {
        const int s0 = esrc[e + 0], s1 = esrc[e + 1];
        const int s2 = esrc[e + 2], s3 = esrc[e + 3];
        const ushort4 v0 = *(const ushort4*)(hp + (size_t)s0 * 512 + co);
        const ushort4 v1 = *(const ushort4*)(hp + (size_t)s1 * 512 + co);
        const ushort4 v2 = *(const ushort4*)(hp + (size_t)s2 * 512 + co);
        const ushort4 v3 = *(const ushort4*)(hp + (size_t)s3 * 512 + co);
        acc = umax4(umax4(umax4(acc, v0), umax4(v1, v2)), v3);
    }
    for (; e < e1; ++e)
        acc = umax4(acc, *(const ushort4*)(hp + (size_t)esrc[e] * 512 + co));
    *(ushort4*)(neigh + (size_t)node * 512 + co) = acc;
}

extern "C" void kernel_launch(void* const* d_in, const int* in_sizes, int n_in,
                              void* d_out, int out_size, void* d_ws, size_t ws_size,
                              hipStream_t stream)
{
    const float* x      = (const float*)d_in[0];
    const int*   src    = (const int*)d_in[1];
    const int*   dst    = (const int*)d_in[2];
    const float* Wlin   = (const float*)d_in[3];
    const float* blin   = (const float*)d_in[4];
    const float* Wpool  = (const float*)d_in[5];
    const float* bpool  = (const float*)d_in[6];
    const float* Wself  = (const float*)d_in[7];
    const float* Wneigh = (const float*)d_in[8];
    const float* bconv  = (const float*)d_in[9];
    const float* gamma  = (const float*)d_in[10];
    const float* beta   = (const float*)d_in[11];

    const size_t NB = (size_t)N_NODES * D_H;  // 5.12M
    char* p = (char*)d_ws;
    unsigned short* hp_b    = (unsigned short*)p; p += NB * 2 * T_ETYPES;  // [N,512]
    unsigned short* neigh_b = (unsigned short*)p; p += NB * 2 * T_ETYPES;  // [N,512]
    unsigned short* h_a     = (unsigned short*)p; p += NB * 2;
    unsigned short* h_b     = (unsigned short*)p; p += NB * 2;
    unsigned short* xb      = (unsigned short*)p; p += (size_t)N_NODES * F_IN * 2;  // 20.48MB
    float*          Rbuf    = (float*)p;          p += (size_t)N_NODES * 512 * 4;   // 40.96MB
    unsigned short* wlin_f  = (unsigned short*)p; p += (size_t)D_H * F_IN * 2;
    const size_t WSZ = (size_t)L_LAYERS * T_ETYPES * D_H * D_H;  // 393216
    unsigned short* wpool_f = (unsigned short*)p; p += WSZ * 2;
    unsigned short* wself_f = (unsigned short*)p; p += WSZ * 2;
    unsigned short* wneigh_f= (unsigned short*)p; p += WSZ * 2;
    int* ip = (int*)p;
    const int NT = T_ETYPES * N_NODES;  // 40000
    int* cnt    = ip; ip += NT;
    int* incl   = ip; ip += NT;
    int* off    = ip; ip += NT + 1;
    int* cursor = ip; ip += NT;
    int* esrc   = ip; ip += T_ETYPES * E_EDGES;
    int* bsum   = ip; ip += 256;

    const dim3 blk(256);
    const dim3 blk512(512);
    const int E2 = T_ETYPES * E_EDGES;
    const dim3 e2grid((E2 + 255) / 256);
    const int nScanBlk = (NT + 255) / 256;  // 157

    // ---- prep: x->bf16 + all weights -> fragment-slab bf16, one dispatch ----
    {
        const int nx8  = N_NODES * F_IN / 8;        // 1,280,000
        const int nl8  = D_H * F_IN / 8;            // 16384
        const int nw8  = (int)(WSZ / 8);            // 49152
        const int tot  = nx8 + nl8 + 3 * nw8;
        prep_kernel<<<dim3((tot + 255) / 256), blk, 0, stream>>>(
            x, xb, nx8,
            Wlin, wlin_f, D_H, F_IN, nl8,
            Wpool, wpool_f, T_ETYPES * D_H, D_H, nw8,   // per layer: [512,256]
            Wself, wself_f, D_H, D_H, nw8,              // per (l,t): [256,256]
            Wneigh, wneigh_f, D_H, D_H, nw8);
    }

    // ---- CSR build, both etypes batched ----
    hipMemsetAsync(cnt, 0, (size_t)NT * sizeof(int), stream);
    count_deg_kernel<<<e2grid, blk, 0, stream>>>(dst, cnt, E2);
    scanA_kernel<<<dim3(nScanBlk), blk, 0, stream>>>(cnt, incl, bsum, NT);
    scanB_kernel<<<dim3(1), blk, 0, stream>>>(bsum, nScanBlk);
    scanC_kernel<<<dim3(nScanBlk), blk, 0, stream>>>(cnt, incl, bsum, off, cursor, NT);
    fill_csr_kernel<<<e2grid, blk, 0, stream>>>(src, dst, cursor, esrc, E2);

    const int MGRP = ((N_NODES + 127) / 128 + 7) / 8;  // 20 row-tile groups (padded)

    // ---- h0 = bf16(xb @ Wlin^T + blin), K=512, CS=2 ----
    gemm_lds<16, 2><<<dim3(MGRP * 16), blk512, 0, stream>>>(
        xb, wlin_f, blin, h_a, N_NODES, D_H, 0);

    unsigned short* h = h_a;
    unsigned short* hn = h_b;
    const dim3 sgrid((2 * N_NODES + 3) / 4);
    const dim3 lngrid(N_NODES / 4);             // 5000, exact
    for (int l = 0; l < L_LAYERS; ++l) {
        // hp[:, t*256:] = bf16(relu(h @ Wpool[l,t]^T + bpool[l,t])), both t, CS=4
        gemm_lds<8, 4><<<dim3(MGRP * 32), blk512, 0, stream>>>(
            h, wpool_f + (size_t)l * T_ETYPES * D_H * D_H,
            bpool + (size_t)l * T_ETYPES * D_H, hp_b, N_NODES, T_ETYPES * D_H, 1);
        // neigh = segment_max per (node, t)
        seg_max_kernel<<<sgrid, blk, 0, stream>>>(hp_b, off, esrc, neigh_b);
        // tail GEMM -> R fp32 (relu'd, bias'd), then LN+sum
        const size_t wlo = (size_t)l * T_ETYPES * D_H * D_H;
        const size_t blo = (size_t)l * T_ETYPES * D_H;
        if (l < L_LAYERS - 1) {
            tail_gemm<1><<<dim3(MGRP * 32), blk512, 0, stream>>>(
                h, neigh_b, wself_f + wlo, wneigh_f + wlo, bconv + blo, Rbuf);
            ln_sum_kernel<0><<<lngrid, blk, 0, stream>>>(
                Rbuf, gamma + blo, beta + blo, hn);
        } else {
            tail_gemm<0><<<dim3(MGRP * 32), blk512, 0, stream>>>(
                h, neigh_b, wself_f + wlo, wneigh_f + wlo, bconv + blo, Rbuf);
            ln_sum_kernel<1><<<lngrid, blk, 0, stream>>>(
                Rbuf, gamma + blo, beta + blo, d_out);
        }
        unsigned short* tmp = h; h = hn; hn = tmp;
    }
}